// Round 5
// baseline (675.136 us; speedup 1.0000x reference)
//
#include <hip/hip_runtime.h>
#include <hip/hip_bf16.h>

using bf16 = __hip_bfloat16;
typedef __attribute__((ext_vector_type(4))) float f4;
typedef __attribute__((ext_vector_type(16))) float f16v;
typedef __attribute__((ext_vector_type(8))) short s8v;
typedef __attribute__((ext_vector_type(4))) short s4v;
typedef __attribute__((ext_vector_type(4))) unsigned int u4v;
typedef unsigned int u32;

__device__ __forceinline__ short f2bf(float x) {
  bf16 h = __float2bfloat16(x);
  return *reinterpret_cast<short*>(&h);
}

__device__ __forceinline__ u32 pkbf(float lo, float hi) {
  return (u32)(unsigned short)f2bf(lo) | ((u32)(unsigned short)f2bf(hi) << 16);
}

__device__ __forceinline__ void gload16(const bf16* g, bf16* l) {
  __builtin_amdgcn_global_load_lds(
      (const __attribute__((address_space(1))) u32*)g,
      (__attribute__((address_space(3))) u32*)l, 16, 0, 0);
}

// swap lanes 32..63 of a with lanes 0..31 of b (v_permlane32_swap_b32)
__device__ __forceinline__ void swp32(u32& a, u32& b, int h) {
#if __has_builtin(__builtin_amdgcn_permlane32_swap)
  typedef __attribute__((ext_vector_type(2))) int i2v;
  i2v r = __builtin_amdgcn_permlane32_swap((int)a, (int)b, false, false);
  a = (u32)r.x;
  b = (u32)r.y;
#else
  u32 as = (u32)__shfl_xor((int)a, 32), bs = (u32)__shfl_xor((int)b, 32);
  u32 an = h ? bs : a, bn = h ? b : as;
  a = an;
  b = bn;
#endif
}

// cross-half (lane ^ 32) max/sum without LDS traffic
__device__ __forceinline__ float xhalf_max(float x) {
#if __has_builtin(__builtin_amdgcn_permlane32_swap)
  typedef __attribute__((ext_vector_type(2))) int i2v;
  i2v r = __builtin_amdgcn_permlane32_swap(__float_as_int(x), __float_as_int(x),
                                           false, false);
  return fmaxf(__int_as_float(r.x), __int_as_float(r.y));
#else
  return fmaxf(x, __shfl_xor(x, 32));
#endif
}
__device__ __forceinline__ float xhalf_sum(float x) {
#if __has_builtin(__builtin_amdgcn_permlane32_swap)
  typedef __attribute__((ext_vector_type(2))) int i2v;
  i2v r = __builtin_amdgcn_permlane32_swap(__float_as_int(x), __float_as_int(x),
                                           false, false);
  return __int_as_float(r.x) + __int_as_float(r.y);
#else
  return x + __shfl_xor(x, 32);
#endif
}

// ------------------------------------------------------------------
// generic fp32 -> bf16, 8 elems/thread
__global__ __launch_bounds__(256) void cvt_bf16(const float* __restrict__ src,
                                                bf16* __restrict__ dst) {
  size_t e = ((size_t)blockIdx.x * 256 + threadIdx.x) << 3;
  f4 a = *(const f4*)(src + e);
  f4 b = *(const f4*)(src + e + 4);
  s8v r = { f2bf(a[0]), f2bf(a[1]), f2bf(a[2]), f2bf(a[3]),
            f2bf(b[0]), f2bf(b[1]), f2bf(b[2]), f2bf(b[3]) };
  *(s8v*)(dst + e) = r;
}

// cache_k [b][kv][p][d] f32 -> kfull [b][kv][p][d] bf16 (p < 1024)
__global__ __launch_bounds__(256) void cvt_cache_k(const float* __restrict__ src,
                                                   bf16* __restrict__ dst) {
  size_t e = ((size_t)blockIdx.x * 256 + threadIdx.x) << 2;
  f4 v = *(const f4*)(src + e);
  unsigned d = (unsigned)(e & 127u), p = (unsigned)((e >> 7) & 1023u), bk = (unsigned)(e >> 17);
  s4v r = { f2bf(v[0]), f2bf(v[1]), f2bf(v[2]), f2bf(v[3]) };
  *(s4v*)(dst + (((size_t)bk * 2048 + p) << 7) + d) = r;
}

// cache_v [b][kv][p][d] f32 -> vt [b][kv][d][p] bf16 (transposed, p < 1024)
__global__ __launch_bounds__(256) void cvt_cache_v(const float* __restrict__ src,
                                                   bf16* __restrict__ dst) {
  size_t e = ((size_t)blockIdx.x * 256 + threadIdx.x) << 2;
  unsigned p = (unsigned)(e & 1023u), d = (unsigned)((e >> 10) & 127u), bk = (unsigned)(e >> 17);
  const float* s = src + (((size_t)bk * 1024 + p) << 7) + d;
  s4v r = { f2bf(s[0]), f2bf(s[128]), f2bf(s[256]), f2bf(s[384]) };
  *(s4v*)(dst + (((size_t)bk * 128 + d) << 11) + p) = r;
}

// ------------------------------------------------------------------
// in-place RoPE on bf16 buffer laid out [hh][sstride][128]; rows soff+s
__global__ __launch_bounds__(256) void rope_kernel(bf16* __restrict__ buf,
                                                   const float* __restrict__ fc,
                                                   const float* __restrict__ fs,
                                                   int sstride, int soff) {
  size_t t = (size_t)blockIdx.x * 256 + threadIdx.x;
  unsigned ip = (unsigned)(t & 63u);
  unsigned s  = (unsigned)((t >> 6) & 1023u);
  unsigned hh = (unsigned)(t >> 16);
  size_t base = ((size_t)hh * sstride + soff + s) * 128 + 2 * ip;
  unsigned u = *(unsigned*)(buf + base);
  float xr = __uint_as_float(u << 16);
  float xi = __uint_as_float(u & 0xffff0000u);
  float c = fc[s * 64 + ip], sn = fs[s * 64 + ip];
  unsigned short r0 = (unsigned short)f2bf(xr * c - xi * sn);
  unsigned short r1 = (unsigned short)f2bf(xr * sn + xi * c);
  *(unsigned*)(buf + base) = (unsigned)r0 | ((unsigned)r1 << 16);
}

// ------------------------------------------------------------------
// 256x256-tile GEMM, BK=64, 8-phase schedule, burst prefetch + counted vmcnt.
// C[m,n] = sum_k A[m,k]*B[n,k]; A,B bf16 row-major [.][K].
// 512 thr = 8 waves (2M x 4N); wave tile 128x64; acc 8x4 frags of 16x16x32.
// LDS (dynamic 128 KiB): A0,A1,B0,B1 tiles of 256x64, XOR-chunk-swizzled.
#define MODE_QKV 0
#define MODE_OUT 1

#define PHASE_TAIL(AC, BC, KS, MH)                                           \
  {                                                                          \
    s8v af[4], bv[4];                                                        \
    const int cofs = ((((KS) * 4) | g) ^ fx) << 3;                           \
    _Pragma("unroll") for (int mi = 0; mi < 4; ++mi)                         \
        af[mi] = *(const s8v*)&(AC)[aRowBase + ((MH)*4 + mi) * 1024 + cofs]; \
    _Pragma("unroll") for (int ni = 0; ni < 4; ++ni)                         \
        bv[ni] = *(const s8v*)&(BC)[bRowBase + ni * 1024 + cofs];            \
    __builtin_amdgcn_s_barrier();                                            \
    asm volatile("s_waitcnt lgkmcnt(0)" ::: "memory");                       \
    __builtin_amdgcn_s_setprio(1);                                           \
    _Pragma("unroll") for (int mi = 0; mi < 4; ++mi)                         \
      _Pragma("unroll") for (int ni = 0; ni < 4; ++ni)                       \
          acc[(MH)*4 + mi][ni] = __builtin_amdgcn_mfma_f32_16x16x32_bf16(    \
              af[mi], bv[ni], acc[(MH)*4 + mi][ni], 0, 0, 0);                \
    __builtin_amdgcn_s_setprio(0);                                           \
    __builtin_amdgcn_s_barrier();                                            \
  }

#define PHASE_HEAD(AC, BC)                                                   \
  {                                                                          \
    __builtin_amdgcn_s_barrier();                                            \
    s8v af[4], bv[4];                                                        \
    const int cofs = (g ^ fx) << 3;                                          \
    _Pragma("unroll") for (int mi = 0; mi < 4; ++mi)                         \
        af[mi] = *(const s8v*)&(AC)[aRowBase + mi * 1024 + cofs];            \
    _Pragma("unroll") for (int ni = 0; ni < 4; ++ni)                         \
        bv[ni] = *(const s8v*)&(BC)[bRowBase + ni * 1024 + cofs];            \
    asm volatile("s_waitcnt lgkmcnt(0)" ::: "memory");                       \
    __builtin_amdgcn_s_setprio(1);                                           \
    _Pragma("unroll") for (int mi = 0; mi < 4; ++mi)                         \
      _Pragma("unroll") for (int ni = 0; ni < 4; ++ni)                       \
          acc[mi][ni] = __builtin_amdgcn_mfma_f32_16x16x32_bf16(             \
              af[mi], bv[ni], acc[mi][ni], 0, 0, 0);                         \
    __builtin_amdgcn_s_setprio(0);                                           \
    __builtin_amdgcn_s_barrier();                                            \
  }

// burst prefetch of next tile (8 loads) then wait for CURRENT tile's 8
// (oldest) to retire -> latency cover = 4 full phases.
#define KTILE(AC, BC, PA, PB, NA, NB, PF)                                    \
  {                                                                          \
    if (PF) {                                                                \
      _Pragma("unroll") for (int i = 0; i < 4; ++i)                          \
          gload16((NA) + i * rstep, (PA) + i * 4096);                        \
      _Pragma("unroll") for (int i = 0; i < 4; ++i)                          \
          gload16((NB) + i * rstep, (PB) + i * 4096);                        \
      asm volatile("s_waitcnt vmcnt(8)" ::: "memory");                       \
    } else {                                                                 \
      asm volatile("s_waitcnt vmcnt(0)" ::: "memory");                       \
    }                                                                        \
    PHASE_HEAD(AC, BC)                                                       \
    PHASE_TAIL(AC, BC, 0, 1)                                                 \
    PHASE_TAIL(AC, BC, 1, 0)                                                 \
    PHASE_TAIL(AC, BC, 1, 1)                                                 \
  }

template <int MODE>
__global__ __launch_bounds__(512, 2) void gemm256(const bf16* __restrict__ A,
                                                  const bf16* __restrict__ B,
                                                  void* __restrict__ o1,
                                                  void* __restrict__ o2,
                                                  void* __restrict__ o3,
                                                  int K, float scale) {
  extern __shared__ bf16 smem[];
  bf16* A0 = smem;
  bf16* A1 = smem + 16384;
  bf16* B0 = smem + 32768;
  bf16* B1 = smem + 49152;

  const int tid = threadIdx.x;
  const int lane = tid & 63;
  const int wid = tid >> 6;
  const int wm = wid >> 2, wn = wid & 3;
  const int fr = lane & 15;
  const int g = lane >> 4;
  const int rg = g << 2;
  const int fx = lane & 7;

  // XCD-bijective block swizzle (nwg % 8 == 0 for all our grids)
  const int gy = gridDim.y;
  int lin = blockIdx.y * gridDim.x + blockIdx.x;
  const int qq = (gridDim.x * gy) >> 3;
  lin = (lin & 7) * qq + (lin >> 3);
  const int bm = lin / gy;
  const int bn = lin % gy;

  // staging: thread covers chunk (r0, c0) swizzled; gload i adds 64 rows
  const int r0 = tid >> 3;
  const int sc = (tid & 7) ^ (r0 & 7);
  const bf16* aptr = A + (size_t)(bm * 256 + r0) * K + sc * 8;
  const bf16* bptr = B + (size_t)(bn * 256 + r0) * K + sc * 8;
  const size_t rstep = (size_t)64 * K;
  const int wofs = (tid & 448) << 3;   // wave-uniform LDS base (elems)
  bf16* pA0 = A0 + wofs; bf16* pA1 = A1 + wofs;
  bf16* pB0 = B0 + wofs; bf16* pB1 = B1 + wofs;

  const int aRowBase = (wm * 128 + fr) * 64;
  const int bRowBase = (wn * 64 + fr) * 64;

  f4 acc[8][4] = {};

  // prologue: stage K-tile 0 into A0/B0 (8 loads in flight, no drain)
#pragma unroll
  for (int i = 0; i < 4; ++i) gload16(aptr + i * rstep, pA0 + i * 4096);
#pragma unroll
  for (int i = 0; i < 4; ++i) gload16(bptr + i * rstep, pB0 + i * 4096);

  const int nk = K >> 6;
  for (int kt = 0; kt < nk; kt += 2) {
    const bf16* na = aptr + (kt + 1) * 64;
    const bf16* nb = bptr + (kt + 1) * 64;
    KTILE(A0, B0, pA1, pB1, na, nb, true)
    const bool pf2 = (kt + 2 < nk);
    const bf16* na2 = aptr + (kt + 2) * 64;
    const bf16* nb2 = bptr + (kt + 2) * 64;
    KTILE(A1, B1, pA0, pB0, na2, nb2, pf2)
  }

  // epilogue
#pragma unroll
  for (int m = 0; m < 8; ++m) {
    const int grow0 = bm * 256 + wm * 128 + m * 16 + rg;
    const int b = grow0 >> 10, s0 = grow0 & 1023;
#pragma unroll
    for (int n = 0; n < 4; ++n) {
      const int gcol = bn * 256 + wn * 64 + n * 16 + fr;
      if constexpr (MODE == MODE_OUT) {
#pragma unroll
        for (int j = 0; j < 4; ++j)
          ((float*)o1)[(size_t)(grow0 + j) * 4096 + gcol] = acc[m][n][j];
      } else {
        if (gcol < 4096) {          // Q (scaled)
          const int h = gcol >> 7, d = gcol & 127;
#pragma unroll
          for (int j = 0; j < 4; ++j)
            ((bf16*)o1)[((((size_t)b * 32 + h) << 10) + s0 + j) * 128 + d] =
                __float2bfloat16(acc[m][n][j] * scale);
        } else if (gcol < 5120) {   // K
          const int c = gcol - 4096, hv = c >> 7, d = c & 127;
#pragma unroll
          for (int j = 0; j < 4; ++j)
            ((bf16*)o2)[(((size_t)b * 8 + hv) * 2048 + 1024 + s0 + j) * 128 + d] =
                __float2bfloat16(acc[m][n][j]);
        } else {                    // V (transposed write)
          const int c = gcol - 5120, hv = c >> 7, d = c & 127;
          s4v r = { f2bf(acc[m][n][0]), f2bf(acc[m][n][1]),
                    f2bf(acc[m][n][2]), f2bf(acc[m][n][3]) };
          *(s4v*)((bf16*)o3 + (((size_t)b * 8 + hv) * 128 + d) * 2048 + 1024 + s0) = r;
        }
      }
    }
  }
}

// ------------------------------------------------------------------
// Flash attention, 8 waves x 32 q-rows, 32x32x16 MFMA, swapped QK^T and PV.
// Q pre-scaled by log2(e)/sqrt(128); softmax in exp2 domain, fully in-register.
// Block swizzle: 16 sibling blocks (same b,kv) contiguous -> same XCD; the
// concurrent KV working set per XCD is ~4 MB = L2 size.
__global__ __launch_bounds__(512) void attn_kernel(const bf16* __restrict__ Q,
                                                   const bf16* __restrict__ Kf,
                                                   const bf16* __restrict__ Vt,
                                                   bf16* __restrict__ O) {
  __shared__ alignas(16) bf16 Kls[2][8192];
  __shared__ alignas(16) bf16 Vls[2][8192];

  const int tid = threadIdx.x;
  const int lane = tid & 63;
  const int w = tid >> 6;
  const int h = lane >> 5;
  const int q31 = lane & 31;
  const int rx = q31 & 7;

  // swizzle: lin_new = (lin&7)*64 + lin>>3; decode so consecutive lin_new
  // enumerate (qb, h-within-kv, kv, b) fastest-first.
  int lin = blockIdx.y * 4 + blockIdx.x;               // 0..511
  lin = (lin & 7) * 64 + (lin >> 3);
  const int qb = lin & 3;
  const int hrem = (lin >> 2) & 3;
  const int pair = lin >> 4;                            // 0..31
  const int b = pair >> 3, kv = pair & 7;
  const int hd = kv * 4 + hrem;

  const size_t qbase = (((size_t)b * 32 + hd) << 10) * 128;
  const size_t kbase = (((size_t)b * 8 + kv) * 2048) * 128;
  const size_t vbase = (((size_t)b * 8 + kv) * 128) * 2048;

  const int qrow = qb * 256 + w * 32 + q31;
  s8v qf[8];
#pragma unroll
  for (int c = 0; c < 8; ++c)
    qf[c] = *(const s8v*)&Q[qbase + (size_t)qrow * 128 + c * 16 + h * 8];

  const int sr = tid >> 3;
  const int swz8 = (((tid & 7) ^ (sr & 7)) << 3);
  const int wbase = w * 512;

  f16v oacc[4] = {};
  float mrun = -3e38f, lrun = 0.f;

  auto stage = [&](int kb, int bufi) {
    const bf16* ksrc = Kf + kbase + (size_t)(kb * 64 + sr) * 128 + swz8;
    gload16(ksrc,      &Kls[bufi][wbase]);
    gload16(ksrc + 64, &Kls[bufi][4096 + wbase]);
    const bf16* vsrc = Vt + vbase + (size_t)sr * 2048 + kb * 64 + swz8;
    gload16(vsrc,                      &Vls[bufi][wbase]);
    gload16(vsrc + (size_t)64 * 2048,  &Vls[bufi][4096 + wbase]);
  };

  stage(0, 0);
  asm volatile("s_waitcnt vmcnt(0)" ::: "memory");
  __syncthreads();

  for (int kb = 0; kb < 32; ++kb) {
    const int bufi = kb & 1;
    if (kb + 1 < 32) stage(kb + 1, bufi ^ 1);

    const bf16* KB = Kls[bufi];
    const bf16* VB = Vls[bufi];

    f16v sac[2] = {};
    __builtin_amdgcn_s_setprio(1);
#pragma unroll
    for (int c = 0; c < 8; ++c) {
      const int cc = 2 * c + h;
      const int cof = (cc >> 3) * 4096 + (((cc & 7) ^ rx) << 3);
      s8v k0 = *(const s8v*)&KB[cof + q31 * 64];
      s8v k1 = *(const s8v*)&KB[cof + (32 + q31) * 64];
      sac[0] = __builtin_amdgcn_mfma_f32_32x32x16_bf16(k0, qf[c], sac[0], 0, 0, 0);
      sac[1] = __builtin_amdgcn_mfma_f32_32x32x16_bf16(k1, qf[c], sac[1], 0, 0, 0);
    }
    __builtin_amdgcn_s_setprio(0);

    float pm = -3e38f;
#pragma unroll
    for (int r = 0; r < 16; ++r) {
      pm = fmaxf(pm, sac[0][r]);
      pm = fmaxf(pm, sac[1][r]);
    }
    pm = xhalf_max(pm);

    const bool skip = __all(pm <= mrun + 8.0f);   // defer-max (T13)
    if (!skip) {
      const float mnew = fmaxf(mrun, pm);
      const float corr = exp2f(mrun - mnew);
      mrun = mnew;
      lrun *= corr;
#pragma unroll
      for (int m = 0; m < 4; ++m)
#pragma unroll
        for (int r = 0; r < 16; ++r) oacc[m][r] *= corr;
    }
    float ls = 0.f;
#pragma unroll
    for (int s = 0; s < 2; ++s)
#pragma unroll
      for (int r = 0; r < 16; ++r) {
        const float p = exp2f(sac[s][r] - mrun);
        sac[s][r] = p;
        ls += p;
      }
    lrun += xhalf_sum(ls);

    // P -> bf16 B-frags for PV, in-register (T12)
    s8v F[4];
#pragma unroll
    for (int s = 0; s < 2; ++s) {
      u32 W[8];
#pragma unroll
      for (int t = 0; t < 8; ++t) W[t] = pkbf(sac[s][2 * t], sac[s][2 * t + 1]);
      swp32(W[0], W[2], h); swp32(W[1], W[3], h);
      swp32(W[4], W[6], h); swp32(W[5], W[7], h);
      union { u32 u[4]; s8v v; } f0, f1;
      f0.u[0] = W[0]; f0.u[1] = W[1]; f0.u[2] = W[2]; f0.u[3] = W[3];
      f1.u[0] = W[4]; f1.u[1] = W[5]; f1.u[2] = W[6]; f1.u[3] = W[7];
      F[s * 2] = f0.v;
      F[s * 2 + 1] = f1.v;
    }

    __builtin_amdgcn_s_setprio(1);
#pragma unroll
    for (int ksg = 0; ksg < 4; ++ksg) {
      const int cc2 = 2 * ksg + h;
      const int vof = ((cc2 ^ rx) << 3);
#pragma unroll
      for (int m = 0; m < 4; ++m) {
        s8v vf = *(const s8v*)&VB[(m * 32 + q31) * 64 + vof];
        oacc[m] = __builtin_amdgcn_mfma_f32_32x32x16_bf16(vf, F[ksg], oacc[m], 0, 0, 0);
      }
    }
    __builtin_amdgcn_s_setprio(0);

    asm volatile("s_waitcnt vmcnt(0)" ::: "memory");
    __syncthreads();
  }

  const float inv = 1.f / lrun;
  bf16* orow = O + ((size_t)b * 1024 + qrow) * 4096 + hd * 128;
#pragma unroll
  for (int m = 0; m < 4; ++m)
#pragma unroll
    for (int r = 0; r < 16; r += 2) {
      const int d = m * 32 + (r & 3) + 8 * (r >> 2) + 4 * h;
      *(u32*)&orow[d] = pkbf(oacc[m][r] * inv, oacc[m][r + 1] * inv);
    }
}

// ------------------------------------------------------------------
extern "C" void kernel_launch(void* const* d_in, const int* in_sizes, int n_in,
                              void* d_out, int out_size, void* d_ws, size_t ws_size,
                              hipStream_t stream) {
  const float* x  = (const float*)d_in[0];
  const float* fc = (const float*)d_in[1];
  const float* fs = (const float*)d_in[2];
  const float* ck = (const float*)d_in[3];
  const float* cv = (const float*)d_in[4];
  const float* wq = (const float*)d_in[5];
  const float* wk = (const float*)d_in[6];
  const float* wv = (const float*)d_in[7];
  const float* wo = (const float*)d_in[8];
  float* out = (float*)d_out;

  char* ws = (char*)d_ws;
  bf16* qr    = (bf16*)(ws);                     // [4][32][1024][128]  32 MiB
  bf16* kfull = (bf16*)(ws + (32u << 20));       // [4][8][2048][128]   16 MiB
  bf16* vt    = (bf16*)(ws + (48u << 20));       // [4][8][128][2048]   16 MiB
  bf16* xb    = (bf16*)(ws + (64u << 20));       // [4096][4096]        32 MiB
  bf16* attn  = xb;                              // aliases xb (dead by then)
  bf16* wqb   = (bf16*)(ws + (96u << 20));       // [4096][4096]        32 MiB
  bf16* wob   = wqb;                             // aliases wqb (dead by then)
  bf16* wkvb  = (bf16*)(ws + (128u << 20));      // [2048][4096] follows wqb contiguously

  hipFuncSetAttribute(reinterpret_cast<const void*>(&gemm256<MODE_QKV>),
                      hipFuncAttributeMaxDynamicSharedMemorySize, 131072);
  hipFuncSetAttribute(reinterpret_cast<const void*>(&gemm256<MODE_OUT>),
                      hipFuncAttributeMaxDynamicSharedMemorySize, 131072);

  cvt_bf16<<<8192, 256, 0, stream>>>(x, xb);
  cvt_bf16<<<8192, 256, 0, stream>>>(wq, wqb);
  cvt_bf16<<<2048, 256, 0, stream>>>(wk, wkvb);
  cvt_bf16<<<2048, 256, 0, stream>>>(wv, wkvb + 4194304);
  cvt_cache_k<<<4096, 256, 0, stream>>>(ck, kfull);
  cvt_cache_v<<<4096, 256, 0, stream>>>(cv, vt);

  // fused QKV projection: B = [wqb | wkvb] contiguous rows, N = 6144
  // Q scale = 1/sqrt(128) * log2(e)  (softmax computed in exp2 domain)
  gemm256<MODE_QKV><<<dim3(16, 24), 512, 131072, stream>>>(
      xb, wqb, qr, kfull, vt, 4096, 0.1275174198520337f);

  cvt_bf16<<<8192, 256, 0, stream>>>(wo, wob);   // after QKV gemm: reuses wqb

  rope_kernel<<<32768, 256, 0, stream>>>(qr, fc, fs, 1024, 0);
  rope_kernel<<<8192, 256, 0, stream>>>(kfull, fc, fs, 2048, 1024);

  attn_kernel<<<dim3(4, 128), 512, 0, stream>>>(qr, kfull, vt, attn);

  gemm256<MODE_OUT><<<dim3(16, 16), 512, 131072, stream>>>(
      attn, wob, out, nullptr, nullptr, 4096, 1.0f);
}

// Round 6
// 619.865 us; speedup vs baseline: 1.0892x; 1.0892x over previous
//
#include <hip/hip_runtime.h>
#include <hip/hip_bf16.h>

using bf16 = __hip_bfloat16;
typedef __attribute__((ext_vector_type(4))) float f4;
typedef __attribute__((ext_vector_type(16))) float f16v;
typedef __attribute__((ext_vector_type(8))) short s8v;
typedef __attribute__((ext_vector_type(4))) short s4v;
typedef __attribute__((ext_vector_type(4))) unsigned int u4v;
typedef unsigned int u32;

__device__ __forceinline__ short f2bf(float x) {
  bf16 h = __float2bfloat16(x);
  return *reinterpret_cast<short*>(&h);
}

__device__ __forceinline__ u32 pkbf(float lo, float hi) {
  return (u32)(unsigned short)f2bf(lo) | ((u32)(unsigned short)f2bf(hi) << 16);
}

__device__ __forceinline__ void gload16(const bf16* g, bf16* l) {
  __builtin_amdgcn_global_load_lds(
      (const __attribute__((address_space(1))) u32*)g,
      (__attribute__((address_space(3))) u32*)l, 16, 0, 0);
}

// swap lanes 32..63 of a with lanes 0..31 of b (v_permlane32_swap_b32)
__device__ __forceinline__ void swp32(u32& a, u32& b, int h) {
#if __has_builtin(__builtin_amdgcn_permlane32_swap)
  typedef __attribute__((ext_vector_type(2))) int i2v;
  i2v r = __builtin_amdgcn_permlane32_swap((int)a, (int)b, false, false);
  a = (u32)r.x;
  b = (u32)r.y;
#else
  u32 as = (u32)__shfl_xor((int)a, 32), bs = (u32)__shfl_xor((int)b, 32);
  u32 an = h ? bs : a, bn = h ? b : as;
  a = an;
  b = bn;
#endif
}

// cross-half (lane ^ 32) max/sum without LDS traffic
__device__ __forceinline__ float xhalf_max(float x) {
#if __has_builtin(__builtin_amdgcn_permlane32_swap)
  typedef __attribute__((ext_vector_type(2))) int i2v;
  i2v r = __builtin_amdgcn_permlane32_swap(__float_as_int(x), __float_as_int(x),
                                           false, false);
  return fmaxf(__int_as_float(r.x), __int_as_float(r.y));
#else
  return fmaxf(x, __shfl_xor(x, 32));
#endif
}
__device__ __forceinline__ float xhalf_sum(float x) {
#if __has_builtin(__builtin_amdgcn_permlane32_swap)
  typedef __attribute__((ext_vector_type(2))) int i2v;
  i2v r = __builtin_amdgcn_permlane32_swap(__float_as_int(x), __float_as_int(x),
                                           false, false);
  return __int_as_float(r.x) + __int_as_float(r.y);
#else
  return x + __shfl_xor(x, 32);
#endif
}

// ------------------------------------------------------------------
// generic fp32 -> bf16, 8 elems/thread
__global__ __launch_bounds__(256) void cvt_bf16(const float* __restrict__ src,
                                                bf16* __restrict__ dst) {
  size_t e = ((size_t)blockIdx.x * 256 + threadIdx.x) << 3;
  f4 a = *(const f4*)(src + e);
  f4 b = *(const f4*)(src + e + 4);
  s8v r = { f2bf(a[0]), f2bf(a[1]), f2bf(a[2]), f2bf(a[3]),
            f2bf(b[0]), f2bf(b[1]), f2bf(b[2]), f2bf(b[3]) };
  *(s8v*)(dst + e) = r;
}

// cache_k [b][kv][p][d] f32 -> kfull [b][kv][p][d] bf16 (p < 1024)
__global__ __launch_bounds__(256) void cvt_cache_k(const float* __restrict__ src,
                                                   bf16* __restrict__ dst) {
  size_t e = ((size_t)blockIdx.x * 256 + threadIdx.x) << 2;
  f4 v = *(const f4*)(src + e);
  unsigned d = (unsigned)(e & 127u), p = (unsigned)((e >> 7) & 1023u), bk = (unsigned)(e >> 17);
  s4v r = { f2bf(v[0]), f2bf(v[1]), f2bf(v[2]), f2bf(v[3]) };
  *(s4v*)(dst + (((size_t)bk * 2048 + p) << 7) + d) = r;
}

// cache_v [b][kv][p][d] f32 -> vt [b][kv][d][p] bf16 (transposed, p < 1024)
__global__ __launch_bounds__(256) void cvt_cache_v(const float* __restrict__ src,
                                                   bf16* __restrict__ dst) {
  size_t e = ((size_t)blockIdx.x * 256 + threadIdx.x) << 2;
  unsigned p = (unsigned)(e & 1023u), d = (unsigned)((e >> 10) & 127u), bk = (unsigned)(e >> 17);
  const float* s = src + (((size_t)bk * 1024 + p) << 7) + d;
  s4v r = { f2bf(s[0]), f2bf(s[128]), f2bf(s[256]), f2bf(s[384]) };
  *(s4v*)(dst + (((size_t)bk * 128 + d) << 11) + p) = r;
}

// ------------------------------------------------------------------
// in-place RoPE on bf16 buffer laid out [hh][sstride][128]; rows soff+s
__global__ __launch_bounds__(256) void rope_kernel(bf16* __restrict__ buf,
                                                   const float* __restrict__ fc,
                                                   const float* __restrict__ fs,
                                                   int sstride, int soff) {
  size_t t = (size_t)blockIdx.x * 256 + threadIdx.x;
  unsigned ip = (unsigned)(t & 63u);
  unsigned s  = (unsigned)((t >> 6) & 1023u);
  unsigned hh = (unsigned)(t >> 16);
  size_t base = ((size_t)hh * sstride + soff + s) * 128 + 2 * ip;
  unsigned u = *(unsigned*)(buf + base);
  float xr = __uint_as_float(u << 16);
  float xi = __uint_as_float(u & 0xffff0000u);
  float c = fc[s * 64 + ip], sn = fs[s * 64 + ip];
  unsigned short r0 = (unsigned short)f2bf(xr * c - xi * sn);
  unsigned short r1 = (unsigned short)f2bf(xr * sn + xi * c);
  *(unsigned*)(buf + base) = (unsigned)r0 | ((unsigned)r1 << 16);
}

// ------------------------------------------------------------------
// 256x256-tile GEMM, BK=64, 8-phase schedule (R4-proven distributed prefetch).
#define MODE_Q   0
#define MODE_OUT 1

#define PHASE_TAIL(AC, BC, KS, MH)                                           \
  {                                                                          \
    s8v af[4], bv[4];                                                        \
    const int cofs = ((((KS) * 4) | g) ^ fx) << 3;                           \
    _Pragma("unroll") for (int mi = 0; mi < 4; ++mi)                         \
        af[mi] = *(const s8v*)&(AC)[aRowBase + ((MH)*4 + mi) * 1024 + cofs]; \
    _Pragma("unroll") for (int ni = 0; ni < 4; ++ni)                         \
        bv[ni] = *(const s8v*)&(BC)[bRowBase + ni * 1024 + cofs];            \
    __builtin_amdgcn_s_barrier();                                            \
    asm volatile("s_waitcnt lgkmcnt(0)" ::: "memory");                       \
    __builtin_amdgcn_s_setprio(1);                                           \
    _Pragma("unroll") for (int mi = 0; mi < 4; ++mi)                         \
      _Pragma("unroll") for (int ni = 0; ni < 4; ++ni)                       \
          acc[(MH)*4 + mi][ni] = __builtin_amdgcn_mfma_f32_16x16x32_bf16(    \
              af[mi], bv[ni], acc[(MH)*4 + mi][ni], 0, 0, 0);                \
    __builtin_amdgcn_s_setprio(0);                                           \
    __builtin_amdgcn_s_barrier();                                            \
  }

#define PHASE_HEAD(AC, BC)                                                   \
  {                                                                          \
    __builtin_amdgcn_s_barrier();                                            \
    s8v af[4], bv[4];                                                        \
    const int cofs = (g ^ fx) << 3;                                          \
    _Pragma("unroll") for (int mi = 0; mi < 4; ++mi)                         \
        af[mi] = *(const s8v*)&(AC)[aRowBase + mi * 1024 + cofs];            \
    _Pragma("unroll") for (int ni = 0; ni < 4; ++ni)                         \
        bv[ni] = *(const s8v*)&(BC)[bRowBase + ni * 1024 + cofs];            \
    asm volatile("s_waitcnt lgkmcnt(0)" ::: "memory");                       \
    __builtin_amdgcn_s_setprio(1);                                           \
    _Pragma("unroll") for (int mi = 0; mi < 4; ++mi)                         \
      _Pragma("unroll") for (int ni = 0; ni < 4; ++ni)                       \
          acc[mi][ni] = __builtin_amdgcn_mfma_f32_16x16x32_bf16(             \
              af[mi], bv[ni], acc[mi][ni], 0, 0, 0);                         \
    __builtin_amdgcn_s_setprio(0);                                           \
    __builtin_amdgcn_s_barrier();                                            \
  }

#define KTILE(AC, BC, PA, PB, NA, NB, PF)                                    \
  {                                                                          \
    if (PF) { gload16((NA), (PA)); gload16((NA) + rstep, (PA) + 4096); }     \
    if (PF) asm volatile("s_waitcnt vmcnt(2)" ::: "memory");                 \
    else    asm volatile("s_waitcnt vmcnt(0)" ::: "memory");                 \
    PHASE_HEAD(AC, BC)                                                       \
    if (PF) { gload16((NA) + 2 * rstep, (PA) + 8192);                        \
              gload16((NA) + 3 * rstep, (PA) + 12288); }                     \
    PHASE_TAIL(AC, BC, 0, 1)                                                 \
    if (PF) { gload16((NB), (PB)); gload16((NB) + rstep, (PB) + 4096); }     \
    PHASE_TAIL(AC, BC, 1, 0)                                                 \
    if (PF) { gload16((NB) + 2 * rstep, (PB) + 8192);                        \
              gload16((NB) + 3 * rstep, (PB) + 12288); }                     \
    PHASE_TAIL(AC, BC, 1, 1)                                                 \
  }

template <int MODE>
__global__ __launch_bounds__(512, 2) void gemm256(const bf16* __restrict__ A,
                                                  const bf16* __restrict__ B,
                                                  void* __restrict__ o1,
                                                  int K, float scale) {
  extern __shared__ bf16 smem[];
  bf16* A0 = smem;
  bf16* A1 = smem + 16384;
  bf16* B0 = smem + 32768;
  bf16* B1 = smem + 49152;

  const int tid = threadIdx.x;
  const int lane = tid & 63;
  const int wid = tid >> 6;
  const int wm = wid >> 2, wn = wid & 3;
  const int fr = lane & 15;
  const int g = lane >> 4;
  const int rg = g << 2;
  const int fx = lane & 7;

  // XCD-bijective block swizzle (nwg % 8 == 0)
  const int gy = gridDim.y;
  int lin = blockIdx.y * gridDim.x + blockIdx.x;
  const int qq = (gridDim.x * gy) >> 3;
  lin = (lin & 7) * qq + (lin >> 3);
  const int bm = lin / gy;
  const int bn = lin % gy;

  const int r0 = tid >> 3;
  const int sc = (tid & 7) ^ (r0 & 7);
  const bf16* aptr = A + (size_t)(bm * 256 + r0) * K + sc * 8;
  const bf16* bptr = B + (size_t)(bn * 256 + r0) * K + sc * 8;
  const size_t rstep = (size_t)64 * K;
  const int wofs = (tid & 448) << 3;
  bf16* pA0 = A0 + wofs; bf16* pA1 = A1 + wofs;
  bf16* pB0 = B0 + wofs; bf16* pB1 = B1 + wofs;

  const int aRowBase = (wm * 128 + fr) * 64;
  const int bRowBase = (wn * 64 + fr) * 64;

  f4 acc[8][4] = {};

#pragma unroll
  for (int i = 0; i < 4; ++i) gload16(aptr + i * rstep, pA0 + i * 4096);
#pragma unroll
  for (int i = 0; i < 4; ++i) gload16(bptr + i * rstep, pB0 + i * 4096);

  const int nk = K >> 6;
  for (int kt = 0; kt < nk; kt += 2) {
    const bf16* na = aptr + (kt + 1) * 64;
    const bf16* nb = bptr + (kt + 1) * 64;
    KTILE(A0, B0, pA1, pB1, na, nb, true)
    const bool pf2 = (kt + 2 < nk);
    const bf16* na2 = aptr + (kt + 2) * 64;
    const bf16* nb2 = bptr + (kt + 2) * 64;
    KTILE(A1, B1, pA0, pB0, na2, nb2, pf2)
  }

#pragma unroll
  for (int m = 0; m < 8; ++m) {
    const int grow0 = bm * 256 + wm * 128 + m * 16 + rg;
    const int b = grow0 >> 10, s0 = grow0 & 1023;
#pragma unroll
    for (int n = 0; n < 4; ++n) {
      const int gcol = bn * 256 + wn * 64 + n * 16 + fr;
      if constexpr (MODE == MODE_OUT) {
#pragma unroll
        for (int j = 0; j < 4; ++j)
          ((float*)o1)[(size_t)(grow0 + j) * 4096 + gcol] = acc[m][n][j];
      } else {  // MODE_Q (scaled scatter to [b][h][s][d])
        const int h = gcol >> 7, d = gcol & 127;
#pragma unroll
        for (int j = 0; j < 4; ++j)
          ((bf16*)o1)[((((size_t)b * 32 + h) << 10) + s0 + j) * 128 + d] =
              __float2bfloat16(acc[m][n][j] * scale);
      }
    }
  }
}

// ------------------------------------------------------------------
// 128x256-tile GEMM for the KV projection (N=2048): grid 32x8 = 256 blocks
// = exactly one dispatch round. 8 waves of 64x64; acc 4x4; 2 phases/K-tile.
// LDS 96 KiB: A 2x(128x64), B 2x(256x64), same XOR-chunk swizzle.
#define PH128(AC, BC, KS, OPEN)                                              \
  {                                                                          \
    if (OPEN) __builtin_amdgcn_s_barrier();                                  \
    s8v af[4], bv[4];                                                        \
    const int cofs = ((((KS) * 4) | g) ^ fx) << 3;                           \
    _Pragma("unroll") for (int mi = 0; mi < 4; ++mi)                         \
        af[mi] = *(const s8v*)&(AC)[aRowBase + mi * 1024 + cofs];            \
    _Pragma("unroll") for (int ni = 0; ni < 4; ++ni)                         \
        bv[ni] = *(const s8v*)&(BC)[bRowBase + ni * 1024 + cofs];            \
    if (!(OPEN)) __builtin_amdgcn_s_barrier();                               \
    asm volatile("s_waitcnt lgkmcnt(0)" ::: "memory");                       \
    __builtin_amdgcn_s_setprio(1);                                           \
    _Pragma("unroll") for (int mi = 0; mi < 4; ++mi)                         \
      _Pragma("unroll") for (int ni = 0; ni < 4; ++ni)                       \
          acc[mi][ni] = __builtin_amdgcn_mfma_f32_16x16x32_bf16(             \
              af[mi], bv[ni], acc[mi][ni], 0, 0, 0);                         \
    __builtin_amdgcn_s_setprio(0);                                           \
    __builtin_amdgcn_s_barrier();                                            \
  }

#define KTILE128(AC, BC, PA, PB, NA, NB, PF)                                 \
  {                                                                          \
    if (PF) { gload16((NB), (PB)); gload16((NB) + rstep, (PB) + 4096); }     \
    if (PF) asm volatile("s_waitcnt vmcnt(2)" ::: "memory");                 \
    else    asm volatile("s_waitcnt vmcnt(0)" ::: "memory");                 \
    PH128(AC, BC, 0, true)                                                   \
    if (PF) { gload16((NB) + 2 * rstep, (PB) + 8192);                        \
              gload16((NB) + 3 * rstep, (PB) + 12288);                       \
              gload16((NA), (PA)); gload16((NA) + rstep, (PA) + 4096); }     \
    PH128(AC, BC, 1, false)                                                  \
  }

__global__ __launch_bounds__(512, 2) void gemm128kv(const bf16* __restrict__ A,
                                                    const bf16* __restrict__ B,
                                                    bf16* __restrict__ kout,
                                                    bf16* __restrict__ vout,
                                                    int K) {
  extern __shared__ bf16 smem[];
  bf16* A0 = smem;
  bf16* A1 = smem + 8192;
  bf16* B0 = smem + 16384;
  bf16* B1 = smem + 32768;

  const int tid = threadIdx.x;
  const int lane = tid & 63;
  const int wid = tid >> 6;
  const int wm = wid >> 2, wn = wid & 3;
  const int fr = lane & 15;
  const int g = lane >> 4;
  const int rg = g << 2;
  const int fx = lane & 7;

  const int gy = gridDim.y;
  int lin = blockIdx.y * gridDim.x + blockIdx.x;
  const int qq = (gridDim.x * gy) >> 3;
  lin = (lin & 7) * qq + (lin >> 3);
  const int bm = lin / gy;
  const int bn = lin % gy;

  const int r0 = tid >> 3;
  const int sc = (tid & 7) ^ (r0 & 7);
  const bf16* aptr = A + (size_t)(bm * 128 + r0) * K + sc * 8;
  const bf16* bptr = B + (size_t)(bn * 256 + r0) * K + sc * 8;
  const size_t rstep = (size_t)64 * K;
  const int wofs = (tid & 448) << 3;
  bf16* pA0 = A0 + wofs; bf16* pA1 = A1 + wofs;
  bf16* pB0 = B0 + wofs; bf16* pB1 = B1 + wofs;

  const int aRowBase = (wm * 64 + fr) * 64;
  const int bRowBase = (wn * 64 + fr) * 64;

  f4 acc[4][4] = {};

  // prologue: tile 0 (A 2 loads + B 4 loads)
  gload16(aptr, pA0); gload16(aptr + rstep, pA0 + 4096);
#pragma unroll
  for (int i = 0; i < 4; ++i) gload16(bptr + i * rstep, pB0 + i * 4096);

  const int nk = K >> 6;
  for (int kt = 0; kt < nk; kt += 2) {
    const bf16* na = aptr + (kt + 1) * 64;
    const bf16* nb = bptr + (kt + 1) * 64;
    KTILE128(A0, B0, pA1, pB1, na, nb, true)
    const bool pf2 = (kt + 2 < nk);
    const bf16* na2 = aptr + (kt + 2) * 64;
    const bf16* nb2 = bptr + (kt + 2) * 64;
    KTILE128(A1, B1, pA0, pB0, na2, nb2, pf2)
  }

  // epilogue: cols 0..1023 = K proj, 1024..2047 = V proj (transposed write)
#pragma unroll
  for (int m = 0; m < 4; ++m) {
    const int grow0 = bm * 128 + wm * 64 + m * 16 + rg;
    const int b = grow0 >> 10, s0 = grow0 & 1023;
#pragma unroll
    for (int n = 0; n < 4; ++n) {
      const int gcol = bn * 256 + wn * 64 + n * 16 + fr;
      if (gcol < 1024) {
        const int hv = gcol >> 7, d = gcol & 127;
#pragma unroll
        for (int j = 0; j < 4; ++j)
          kout[(((size_t)b * 8 + hv) * 2048 + 1024 + s0 + j) * 128 + d] =
              __float2bfloat16(acc[m][n][j]);
      } else {
        const int c = gcol - 1024, hv = c >> 7, d = c & 127;
        s4v r = { f2bf(acc[m][n][0]), f2bf(acc[m][n][1]),
                  f2bf(acc[m][n][2]), f2bf(acc[m][n][3]) };
        *(s4v*)(vout + (((size_t)b * 8 + hv) * 128 + d) * 2048 + 1024 + s0) = r;
      }
    }
  }
}

// ------------------------------------------------------------------
// Flash attention, 8 waves x 32 q-rows, 32x32x16 MFMA, swapped QK^T and PV.
// Q pre-scaled by log2(e)/sqrt(128); softmax in exp2 domain, in-register.
// Block swizzle: 16 sibling blocks (same b,kv) on one XCD (KV fits 4MB L2).
__global__ __launch_bounds__(512) void attn_kernel(const bf16* __restrict__ Q,
                                                   const bf16* __restrict__ Kf,
                                                   const bf16* __restrict__ Vt,
                                                   bf16* __restrict__ O) {
  __shared__ alignas(16) bf16 Kls[2][8192];
  __shared__ alignas(16) bf16 Vls[2][8192];

  const int tid = threadIdx.x;
  const int lane = tid & 63;
  const int w = tid >> 6;
  const int h = lane >> 5;
  const int q31 = lane & 31;
  const int rx = q31 & 7;

  int lin = blockIdx.y * 4 + blockIdx.x;               // 0..511
  lin = (lin & 7) * 64 + (lin >> 3);
  const int qb = lin & 3;
  const int hrem = (lin >> 2) & 3;
  const int pair = lin >> 4;                            // 0..31
  const int b = pair >> 3, kv = pair & 7;
  const int hd = kv * 4 + hrem;

  const size_t qbase = (((size_t)b * 32 + hd) << 10) * 128;
  const size_t kbase = (((size_t)b * 8 + kv) * 2048) * 128;
  const size_t vbase = (((size_t)b * 8 + kv) * 128) * 2048;

  const int qrow = qb * 256 + w * 32 + q31;
  s8v qf[8];
#pragma unroll
  for (int c = 0; c < 8; ++c)
    qf[c] = *(const s8v*)&Q[qbase + (size_t)qrow * 128 + c * 16 + h * 8];

  const int sr = tid >> 3;
  const int swz8 = (((tid & 7) ^ (sr & 7)) << 3);
  const int wbase = w * 512;

  f16v oacc[4] = {};
  float mrun = -3e38f, lrun = 0.f;

  auto stage = [&](int kb, int bufi) {
    const bf16* ksrc = Kf + kbase + (size_t)(kb * 64 + sr) * 128 + swz8;
    gload16(ksrc,      &Kls[bufi][wbase]);
    gload16(ksrc + 64, &Kls[bufi][4096 + wbase]);
    const bf16* vsrc = Vt + vbase + (size_t)sr * 2048 + kb * 64 + swz8;
    gload16(vsrc,                      &Vls[bufi][wbase]);
    gload16(vsrc + (size_t)64 * 2048,  &Vls[bufi][4096 + wbase]);
  };

  stage(0, 0);
  asm volatile("s_waitcnt vmcnt(0)" ::: "memory");
  __syncthreads();

  for (int kb = 0; kb < 32; ++kb) {
    const int bufi = kb & 1;
    if (kb + 1 < 32) stage(kb + 1, bufi ^ 1);

    const bf16* KB = Kls[bufi];
    const bf16* VB = Vls[bufi];

    f16v sac[2] = {};
    __builtin_amdgcn_s_setprio(1);
#pragma unroll
    for (int c = 0; c < 8; ++c) {
      const int cc = 2 * c + h;
      const int cof = (cc >> 3) * 4096 + (((cc & 7) ^ rx) << 3);
      s8v k0 = *(const s8v*)&KB[cof + q31 * 64];
      s8v k1 = *(const s8v*)&KB[cof + (32 + q31) * 64];
      sac[0] = __builtin_amdgcn_mfma_f32_32x32x16_bf16(k0, qf[c], sac[0], 0, 0, 0);
      sac[1] = __builtin_amdgcn_mfma_f32_32x32x16_bf16(k1, qf[c], sac[1], 0, 0, 0);
    }
    __builtin_amdgcn_s_setprio(0);

    float pm = -3e38f;
#pragma unroll
    for (int r = 0; r < 16; ++r) {
      pm = fmaxf(pm, sac[0][r]);
      pm = fmaxf(pm, sac[1][r]);
    }
    pm = xhalf_max(pm);

    const bool skip = __all(pm <= mrun + 8.0f);   // defer-max (T13)
    if (!skip) {
      const float mnew = fmaxf(mrun, pm);
      const float corr = exp2f(mrun - mnew);
      mrun = mnew;
      lrun *= corr;
#pragma unroll
      for (int m = 0; m < 4; ++m)
#pragma unroll
        for (int r = 0; r < 16; ++r) oacc[m][r] *= corr;
    }
    float ls = 0.f;
#pragma unroll
    for (int s = 0; s < 2; ++s)
#pragma unroll
      for (int r = 0; r < 16; ++r) {
        const float p = exp2f(sac[s][r] - mrun);
        sac[s][r] = p;
        ls += p;
      }
    lrun += xhalf_sum(ls);

    // P -> bf16 B-frags for PV, in-register (T12)
    s8v F[4];
#pragma unroll
    for (int s = 0; s < 2; ++s) {
      u32 W[8];
#pragma unroll
      for (int t = 0; t < 8; ++t) W[t] = pkbf(sac[s][2 * t], sac[s][2 * t + 1]);
      swp32(W[0], W[2], h); swp32(W[1], W[3], h);
      swp32(W[4], W[6], h); swp32(W[5], W[7], h);
      union { u32 u[4]; s8v v; } f0, f1;
      f0.u[0] = W[0]; f0.u[1] = W[1]; f0.u[2] = W[2]; f0.u[3] = W[3];
      f1.u[0] = W[4]; f1.u[1] = W[5]; f1.u[2] = W[6]; f1.u[3] = W[7];
      F[s * 2] = f0.v;
      F[s * 2 + 1] = f1.v;
    }

    __builtin_amdgcn_s_setprio(1);
#pragma unroll
    for (int ksg = 0; ksg < 4; ++ksg) {
      const int cc2 = 2 * ksg + h;
      const int vof = ((cc2 ^ rx) << 3);
#pragma unroll
      for (int m = 0; m < 4; ++m) {
        s8v vf = *(const s8v*)&VB[(m * 32 + q31) * 64 + vof];
        oacc[m] = __builtin_amdgcn_mfma_f32_32x32x16_bf16(vf, F[ksg], oacc[m], 0, 0, 0);
      }
    }
    __builtin_amdgcn_s_setprio(0);

    asm volatile("s_waitcnt vmcnt(0)" ::: "memory");
    __syncthreads();
  }

  const float inv = 1.f / lrun;
  bf16* orow = O + ((size_t)b * 1024 + qrow) * 4096 + hd * 128;
#pragma unroll
  for (int m = 0; m < 4; ++m)
#pragma unroll
    for (int r = 0; r < 16; r += 2) {
      const int d = m * 32 + (r & 3) + 8 * (r >> 2) + 4 * h;
      *(u32*)&orow[d] = pkbf(oacc[m][r] * inv, oacc[m][r + 1] * inv);
    }
}

// ------------------------------------------------------------------
extern "C" void kernel_launch(void* const* d_in, const int* in_sizes, int n_in,
                              void* d_out, int out_size, void* d_ws, size_t ws_size,
                              hipStream_t stream) {
  const float* x  = (const float*)d_in[0];
  const float* fc = (const float*)d_in[1];
  const float* fs = (const float*)d_in[2];
  const float* ck = (const float*)d_in[3];
  const float* cv = (const float*)d_in[4];
  const float* wq = (const float*)d_in[5];
  const float* wk = (const float*)d_in[6];
  const float* wv = (const float*)d_in[7];
  const float* wo = (const float*)d_in[8];
  float* out = (float*)d_out;

  char* ws = (char*)d_ws;
  bf16* qr    = (bf16*)(ws);                     // [4][32][1024][128]  32 MiB
  bf16* kfull = (bf16*)(ws + (32u << 20));       // [4][8][2048][128]   16 MiB
  bf16* vt    = (bf16*)(ws + (48u << 20));       // [4][8][128][2048]   16 MiB
  bf16* xb    = (bf16*)(ws + (64u << 20));       // [4096][4096]        32 MiB
  bf16* attn  = xb;                              // aliases xb (dead by then)
  bf16* wqb   = (bf16*)(ws + (96u << 20));       // [4096][4096]        32 MiB
  bf16* wob   = wqb;                             // aliases wqb (dead by then)
  bf16* wkvb  = (bf16*)(ws + (128u << 20));      // [2048][4096]        16 MiB

  hipFuncSetAttribute(reinterpret_cast<const void*>(&gemm256<MODE_Q>),
                      hipFuncAttributeMaxDynamicSharedMemorySize, 131072);
  hipFuncSetAttribute(reinterpret_cast<const void*>(&gemm256<MODE_OUT>),
                      hipFuncAttributeMaxDynamicSharedMemorySize, 131072);
  hipFuncSetAttribute(reinterpret_cast<const void*>(&gemm128kv),
                      hipFuncAttributeMaxDynamicSharedMemorySize, 98304);

  cvt_bf16<<<8192, 256, 0, stream>>>(x, xb);
  cvt_bf16<<<8192, 256, 0, stream>>>(wq, wqb);
  cvt_bf16<<<2048, 256, 0, stream>>>(wk, wkvb);
  cvt_bf16<<<2048, 256, 0, stream>>>(wv, wkvb + 4194304);
  cvt_cache_k<<<4096, 256, 0, stream>>>(ck, kfull);
  cvt_cache_v<<<4096, 256, 0, stream>>>(cv, vt);

  // Q scale = 1/sqrt(128) * log2(e)  (softmax computed in exp2 domain)
  gemm256<MODE_Q><<<dim3(16, 16), 512, 131072, stream>>>(
      xb, wqb, qr, 4096, 0.1275174198520337f);
  gemm128kv<<<dim3(32, 8), 512, 98304, stream>>>(xb, wkvb, kfull, vt, 4096);

  cvt_bf16<<<8192, 256, 0, stream>>>(wo, wob);   // after Q gemm: reuses wqb

  rope_kernel<<<32768, 256, 0, stream>>>(qr, fc, fs, 1024, 0);
  rope_kernel<<<8192, 256, 0, stream>>>(kfull, fc, fs, 2048, 1024);

  attn_kernel<<<dim3(4, 128), 512, 0, stream>>>(qr, kfull, vt, attn);

  gemm256<MODE_OUT><<<dim3(16, 16), 512, 131072, stream>>>(
      attn, wob, out, 4096, 1.0f);
}

// Round 9
// 618.572 us; speedup vs baseline: 1.0914x; 1.0021x over previous
//
#include <hip/hip_runtime.h>
#include <hip/hip_bf16.h>

using bf16 = __hip_bfloat16;
typedef __attribute__((ext_vector_type(4))) float f4;
typedef __attribute__((ext_vector_type(16))) float f16v;
typedef __attribute__((ext_vector_type(8))) short s8v;
typedef __attribute__((ext_vector_type(4))) short s4v;
typedef __attribute__((ext_vector_type(4))) unsigned int u4v;
typedef unsigned int u32;

__device__ __forceinline__ short f2bf(float x) {
  bf16 h = __float2bfloat16(x);
  return *reinterpret_cast<short*>(&h);
}

__device__ __forceinline__ u32 pkbf(float lo, float hi) {
  return (u32)(unsigned short)f2bf(lo) | ((u32)(unsigned short)f2bf(hi) << 16);
}

__device__ __forceinline__ void gload16(const bf16* g, bf16* l) {
  __builtin_amdgcn_global_load_lds(
      (const __attribute__((address_space(1))) u32*)g,
      (__attribute__((address_space(3))) u32*)l, 16, 0, 0);
}

// ------------------------------------------------------------------
// generic fp32 -> bf16, 8 elems/thread
__global__ __launch_bounds__(256) void cvt_bf16(const float* __restrict__ src,
                                                bf16* __restrict__ dst) {
  size_t e = ((size_t)blockIdx.x * 256 + threadIdx.x) << 3;
  f4 a = *(const f4*)(src + e);
  f4 b = *(const f4*)(src + e + 4);
  s8v r = { f2bf(a[0]), f2bf(a[1]), f2bf(a[2]), f2bf(a[3]),
            f2bf(b[0]), f2bf(b[1]), f2bf(b[2]), f2bf(b[3]) };
  *(s8v*)(dst + e) = r;
}

// cache_k [b][kv][p][d] f32 -> kfull [b][kv][p][d] bf16 (p < 1024)
__global__ __launch_bounds__(256) void cvt_cache_k(const float* __restrict__ src,
                                                   bf16* __restrict__ dst) {
  size_t e = ((size_t)blockIdx.x * 256 + threadIdx.x) << 2;
  f4 v = *(const f4*)(src + e);
  unsigned d = (unsigned)(e & 127u), p = (unsigned)((e >> 7) & 1023u), bk = (unsigned)(e >> 17);
  s4v r = { f2bf(v[0]), f2bf(v[1]), f2bf(v[2]), f2bf(v[3]) };
  *(s4v*)(dst + (((size_t)bk * 2048 + p) << 7) + d) = r;
}

// cache_v [b][kv][p][d] f32 -> vt [b][kv][d][p] bf16 (transposed, p < 1024)
__global__ __launch_bounds__(256) void cvt_cache_v(const float* __restrict__ src,
                                                   bf16* __restrict__ dst) {
  size_t e = ((size_t)blockIdx.x * 256 + threadIdx.x) << 2;
  unsigned p = (unsigned)(e & 1023u), d = (unsigned)((e >> 10) & 127u), bk = (unsigned)(e >> 17);
  const float* s = src + (((size_t)bk * 1024 + p) << 7) + d;
  s4v r = { f2bf(s[0]), f2bf(s[128]), f2bf(s[256]), f2bf(s[384]) };
  *(s4v*)(dst + (((size_t)bk * 128 + d) << 11) + p) = r;
}

// ------------------------------------------------------------------
// in-place RoPE on bf16 buffer laid out [hh][sstride][128]; rows soff+s
__global__ __launch_bounds__(256) void rope_kernel(bf16* __restrict__ buf,
                                                   const float* __restrict__ fc,
                                                   const float* __restrict__ fs,
                                                   int sstride, int soff) {
  size_t t = (size_t)blockIdx.x * 256 + threadIdx.x;
  unsigned ip = (unsigned)(t & 63u);
  unsigned s  = (unsigned)((t >> 6) & 1023u);
  unsigned hh = (unsigned)(t >> 16);
  size_t base = ((size_t)hh * sstride + soff + s) * 128 + 2 * ip;
  unsigned u = *(unsigned*)(buf + base);
  float xr = __uint_as_float(u << 16);
  float xi = __uint_as_float(u & 0xffff0000u);
  float c = fc[s * 64 + ip], sn = fs[s * 64 + ip];
  unsigned short r0 = (unsigned short)f2bf(xr * c - xi * sn);
  unsigned short r1 = (unsigned short)f2bf(xr * sn + xi * c);
  *(unsigned*)(buf + base) = (unsigned)r0 | ((unsigned)r1 << 16);
}

// ------------------------------------------------------------------
// 256x256-tile GEMM, BK=64, 8-phase schedule (R4-proven distributed prefetch).
#define MODE_Q   0
#define MODE_OUT 1

#define PHASE_TAIL(AC, BC, KS, MH)                                           \
  {                                                                          \
    s8v af[4], bv[4];                                                        \
    const int cofs = ((((KS) * 4) | g) ^ fx) << 3;                           \
    _Pragma("unroll") for (int mi = 0; mi < 4; ++mi)                         \
        af[mi] = *(const s8v*)&(AC)[aRowBase + ((MH)*4 + mi) * 1024 + cofs]; \
    _Pragma("unroll") for (int ni = 0; ni < 4; ++ni)                         \
        bv[ni] = *(const s8v*)&(BC)[bRowBase + ni * 1024 + cofs];            \
    __builtin_amdgcn_s_barrier();                                            \
    asm volatile("s_waitcnt lgkmcnt(0)" ::: "memory");                       \
    __builtin_amdgcn_s_setprio(1);                                           \
    _Pragma("unroll") for (int mi = 0; mi < 4; ++mi)                         \
      _Pragma("unroll") for (int ni = 0; ni < 4; ++ni)                       \
          acc[(MH)*4 + mi][ni] = __builtin_amdgcn_mfma_f32_16x16x32_bf16(    \
              af[mi], bv[ni], acc[(MH)*4 + mi][ni], 0, 0, 0);                \
    __builtin_amdgcn_s_setprio(0);                                           \
    __builtin_amdgcn_s_barrier();                                            \
  }

#define PHASE_HEAD(AC, BC)                                                   \
  {                                                                          \
    __builtin_amdgcn_s_barrier();                                            \
    s8v af[4], bv[4];                                                        \
    const int cofs = (g ^ fx) << 3;                                          \
    _Pragma("unroll") for (int mi = 0; mi < 4; ++mi)                         \
        af[mi] = *(const s8v*)&(AC)[aRowBase + mi * 1024 + cofs];            \
    _Pragma("unroll") for (int ni = 0; ni < 4; ++ni)                         \
        bv[ni] = *(const s8v*)&(BC)[bRowBase + ni * 1024 + cofs];            \
    asm volatile("s_waitcnt lgkmcnt(0)" ::: "memory");                       \
    __builtin_amdgcn_s_setprio(1);                                           \
    _Pragma("unroll") for (int mi = 0; mi < 4; ++mi)                         \
      _Pragma("unroll") for (int ni = 0; ni < 4; ++ni)                       \
          acc[mi][ni] = __builtin_amdgcn_mfma_f32_16x16x32_bf16(             \
              af[mi], bv[ni], acc[mi][ni], 0, 0, 0);                         \
    __builtin_amdgcn_s_setprio(0);                                           \
    __builtin_amdgcn_s_barrier();                                            \
  }

#define KTILE(AC, BC, PA, PB, NA, NB, PF)                                    \
  {                                                                          \
    if (PF) { gload16((NA), (PA)); gload16((NA) + rstep, (PA) + 4096); }     \
    if (PF) asm volatile("s_waitcnt vmcnt(2)" ::: "memory");                 \
    else    asm volatile("s_waitcnt vmcnt(0)" ::: "memory");                 \
    PHASE_HEAD(AC, BC)                                                       \
    if (PF) { gload16((NA) + 2 * rstep, (PA) + 8192);                        \
              gload16((NA) + 3 * rstep, (PA) + 12288); }                     \
    PHASE_TAIL(AC, BC, 0, 1)                                                 \
    if (PF) { gload16((NB), (PB)); gload16((NB) + rstep, (PB) + 4096); }     \
    PHASE_TAIL(AC, BC, 1, 0)                                                 \
    if (PF) { gload16((NB) + 2 * rstep, (PB) + 8192);                        \
              gload16((NB) + 3 * rstep, (PB) + 12288); }                     \
    PHASE_TAIL(AC, BC, 1, 1)                                                 \
  }

template <int MODE>
__global__ __launch_bounds__(512, 2) void gemm256(const bf16* __restrict__ A,
                                                  const bf16* __restrict__ B,
                                                  void* __restrict__ o1,
                                                  int K, float scale) {
  extern __shared__ bf16 smem[];
  bf16* A0 = smem;
  bf16* A1 = smem + 16384;
  bf16* B0 = smem + 32768;
  bf16* B1 = smem + 49152;

  const int tid = threadIdx.x;
  const int lane = tid & 63;
  const int wid = tid >> 6;
  const int wm = wid >> 2, wn = wid & 3;
  const int fr = lane & 15;
  const int g = lane >> 4;
  const int rg = g << 2;
  const int fx = lane & 7;

  // XCD-bijective block swizzle (nwg % 8 == 0)
  const int gy = gridDim.y;
  int lin = blockIdx.y * gridDim.x + blockIdx.x;
  const int qq = (gridDim.x * gy) >> 3;
  lin = (lin & 7) * qq + (lin >> 3);
  const int bm = lin / gy;
  const int bn = lin % gy;

  const int r0 = tid >> 3;
  const int sc = (tid & 7) ^ (r0 & 7);
  const bf16* aptr = A + (size_t)(bm * 256 + r0) * K + sc * 8;
  const bf16* bptr = B + (size_t)(bn * 256 + r0) * K + sc * 8;
  const size_t rstep = (size_t)64 * K;
  const int wofs = (tid & 448) << 3;
  bf16* pA0 = A0 + wofs; bf16* pA1 = A1 + wofs;
  bf16* pB0 = B0 + wofs; bf16* pB1 = B1 + wofs;

  const int aRowBase = (wm * 128 + fr) * 64;
  const int bRowBase = (wn * 64 + fr) * 64;

  f4 acc[8][4] = {};

#pragma unroll
  for (int i = 0; i < 4; ++i) gload16(aptr + i * rstep, pA0 + i * 4096);
#pragma unroll
  for (int i = 0; i < 4; ++i) gload16(bptr + i * rstep, pB0 + i * 4096);

  const int nk = K >> 6;
  for (int kt = 0; kt < nk; kt += 2) {
    const bf16* na = aptr + (kt + 1) * 64;
    const bf16* nb = bptr + (kt + 1) * 64;
    KTILE(A0, B0, pA1, pB1, na, nb, true)
    const bool pf2 = (kt + 2 < nk);
    const bf16* na2 = aptr + (kt + 2) * 64;
    const bf16* nb2 = bptr + (kt + 2) * 64;
    KTILE(A1, B1, pA0, pB0, na2, nb2, pf2)
  }

#pragma unroll
  for (int m = 0; m < 8; ++m) {
    const int grow0 = bm * 256 + wm * 128 + m * 16 + rg;
    const int b = grow0 >> 10, s0 = grow0 & 1023;
#pragma unroll
    for (int n = 0; n < 4; ++n) {
      const int gcol = bn * 256 + wn * 64 + n * 16 + fr;
      if constexpr (MODE == MODE_OUT) {
#pragma unroll
        for (int j = 0; j < 4; ++j)
          ((float*)o1)[(size_t)(grow0 + j) * 4096 + gcol] = acc[m][n][j];
      } else {  // MODE_Q (scaled scatter to [b][h][s][d])
        const int h = gcol >> 7, d = gcol & 127;
#pragma unroll
        for (int j = 0; j < 4; ++j)
          ((bf16*)o1)[((((size_t)b * 32 + h) << 10) + s0 + j) * 128 + d] =
              __float2bfloat16(acc[m][n][j] * scale);
      }
    }
  }
}

// ------------------------------------------------------------------
// 128x256-tile GEMM for the KV projection (N=2048): grid 32x8 = 256 blocks.
#define PH128(AC, BC, KS, OPEN)                                              \
  {                                                                          \
    if (OPEN) __builtin_amdgcn_s_barrier();                                  \
    s8v af[4], bv[4];                                                        \
    const int cofs = ((((KS) * 4) | g) ^ fx) << 3;                           \
    _Pragma("unroll") for (int mi = 0; mi < 4; ++mi)                         \
        af[mi] = *(const s8v*)&(AC)[aRowBase + mi * 1024 + cofs];            \
    _Pragma("unroll") for (int ni = 0; ni < 4; ++ni)                         \
        bv[ni] = *(const s8v*)&(BC)[bRowBase + ni * 1024 + cofs];            \
    if (!(OPEN)) __builtin_amdgcn_s_barrier();                               \
    asm volatile("s_waitcnt lgkmcnt(0)" ::: "memory");                       \
    __builtin_amdgcn_s_setprio(1);                                           \
    _Pragma("unroll") for (int mi = 0; mi < 4; ++mi)                         \
      _Pragma("unroll") for (int ni = 0; ni < 4; ++ni)                       \
          acc[mi][ni] = __builtin_amdgcn_mfma_f32_16x16x32_bf16(             \
              af[mi], bv[ni], acc[mi][ni], 0, 0, 0);                         \
    __builtin_amdgcn_s_setprio(0);                                           \
    __builtin_amdgcn_s_barrier();                                            \
  }

#define KTILE128(AC, BC, PA, PB, NA, NB, PF)                                 \
  {                                                                          \
    if (PF) { gload16((NB), (PB)); gload16((NB) + rstep, (PB) + 4096); }     \
    if (PF) asm volatile("s_waitcnt vmcnt(2)" ::: "memory");                 \
    else    asm volatile("s_waitcnt vmcnt(0)" ::: "memory");                 \
    PH128(AC, BC, 0, true)                                                   \
    if (PF) { gload16((NB) + 2 * rstep, (PB) + 8192);                        \
              gload16((NB) + 3 * rstep, (PB) + 12288);                       \
              gload16((NA), (PA)); gload16((NA) + rstep, (PA) + 4096); }     \
    PH128(AC, BC, 1, false)                                                  \
  }

__global__ __launch_bounds__(512, 2) void gemm128kv(const bf16* __restrict__ A,
                                                    const bf16* __restrict__ B,
                                                    bf16* __restrict__ kout,
                                                    bf16* __restrict__ vout,
                                                    int K) {
  extern __shared__ bf16 smem[];
  bf16* A0 = smem;
  bf16* A1 = smem + 8192;
  bf16* B0 = smem + 16384;
  bf16* B1 = smem + 32768;

  const int tid = threadIdx.x;
  const int lane = tid & 63;
  const int wid = tid >> 6;
  const int wm = wid >> 2, wn = wid & 3;
  const int fr = lane & 15;
  const int g = lane >> 4;
  const int rg = g << 2;
  const int fx = lane & 7;

  const int gy = gridDim.y;
  int lin = blockIdx.y * gridDim.x + blockIdx.x;
  const int qq = (gridDim.x * gy) >> 3;
  lin = (lin & 7) * qq + (lin >> 3);
  const int bm = lin / gy;
  const int bn = lin % gy;

  const int r0 = tid >> 3;
  const int sc = (tid & 7) ^ (r0 & 7);
  const bf16* aptr = A + (size_t)(bm * 128 + r0) * K + sc * 8;
  const bf16* bptr = B + (size_t)(bn * 256 + r0) * K + sc * 8;
  const size_t rstep = (size_t)64 * K;
  const int wofs = (tid & 448) << 3;
  bf16* pA0 = A0 + wofs; bf16* pA1 = A1 + wofs;
  bf16* pB0 = B0 + wofs; bf16* pB1 = B1 + wofs;

  const int aRowBase = (wm * 64 + fr) * 64;
  const int bRowBase = (wn * 64 + fr) * 64;

  f4 acc[4][4] = {};

  gload16(aptr, pA0); gload16(aptr + rstep, pA0 + 4096);
#pragma unroll
  for (int i = 0; i < 4; ++i) gload16(bptr + i * rstep, pB0 + i * 4096);

  const int nk = K >> 6;
  for (int kt = 0; kt < nk; kt += 2) {
    const bf16* na = aptr + (kt + 1) * 64;
    const bf16* nb = bptr + (kt + 1) * 64;
    KTILE128(A0, B0, pA1, pB1, na, nb, true)
    const bool pf2 = (kt + 2 < nk);
    const bf16* na2 = aptr + (kt + 2) * 64;
    const bf16* nb2 = bptr + (kt + 2) * 64;
    KTILE128(A1, B1, pA0, pB0, na2, nb2, pf2)
  }

  // epilogue: cols 0..1023 = K proj, 1024..2047 = V proj (transposed write)
#pragma unroll
  for (int m = 0; m < 4; ++m) {
    const int grow0 = bm * 128 + wm * 64 + m * 16 + rg;
    const int b = grow0 >> 10, s0 = grow0 & 1023;
#pragma unroll
    for (int n = 0; n < 4; ++n) {
      const int gcol = bn * 256 + wn * 64 + n * 16 + fr;
      if (gcol < 1024) {
        const int hv = gcol >> 7, d = gcol & 127;
#pragma unroll
        for (int j = 0; j < 4; ++j)
          kout[(((size_t)b * 8 + hv) * 2048 + 1024 + s0 + j) * 128 + d] =
              __float2bfloat16(acc[m][n][j]);
      } else {
        const int c = gcol - 1024, hv = c >> 7, d = c & 127;
        s4v r = { f2bf(acc[m][n][0]), f2bf(acc[m][n][1]),
                  f2bf(acc[m][n][2]), f2bf(acc[m][n][3]) };
        *(s4v*)(vout + (((size_t)b * 8 + hv) * 128 + d) * 2048 + 1024 + s0) = r;
      }
    }
  }
}

// ------------------------------------------------------------------
// Flash attention, 8 waves x 32 q-rows, 32x32x16 MFMA, swapped QK^T and PV.
// KEY-PERMUTED QK^T: A-row m of QK^T reads K[perm(m)] where perm swaps bits
// 2<->3 of the row index. Then lane-half h holds exactly physical keys
// {16t+8h+j}, so the PV B-fragment is 8 CONSECUTIVE sac values -> no
// cross-lane exchange at all. Row-sum via ones-A MFMA (lacc). The only
// cross-lane op is one __shfl_xor(pm,32) for the running max (proven R3/R6).
__global__ __launch_bounds__(512) void attn_kernel(const bf16* __restrict__ Q,
                                                   const bf16* __restrict__ Kf,
                                                   const bf16* __restrict__ Vt,
                                                   bf16* __restrict__ O) {
  __shared__ alignas(16) bf16 Kls[2][8192];
  __shared__ alignas(16) bf16 Vls[2][8192];

  const int tid = threadIdx.x;
  const int lane = tid & 63;
  const int w = tid >> 6;
  const int h = lane >> 5;
  const int q31 = lane & 31;
  // permuted key row: swap bits 2 and 3 of q31
  const int pq = (q31 & 19) | ((q31 & 4) << 1) | ((q31 & 8) >> 1);
  const int rxK = pq & 7;    // read-side swizzle key for K rows
  const int rxV = q31 & 7;   // read-side swizzle key for V rows (d-rows)

  int lin = blockIdx.y * 4 + blockIdx.x;               // 0..511
  lin = (lin & 7) * 64 + (lin >> 3);
  const int qb = lin & 3;
  const int hrem = (lin >> 2) & 3;
  const int pair = lin >> 4;                            // 0..31
  const int b = pair >> 3, kv = pair & 7;
  const int hd = kv * 4 + hrem;

  const size_t qbase = (((size_t)b * 32 + hd) << 10) * 128;
  const size_t kbase = (((size_t)b * 8 + kv) * 2048) * 128;
  const size_t vbase = (((size_t)b * 8 + kv) * 128) * 2048;

  const int qrow = qb * 256 + w * 32 + q31;
  s8v qf[8];
#pragma unroll
  for (int c = 0; c < 8; ++c)
    qf[c] = *(const s8v*)&Q[qbase + (size_t)qrow * 128 + c * 16 + h * 8];

  // ones A-fragment for the row-sum MFMA
  union { u32 u[4]; s8v v; } onesu;
#pragma unroll
  for (int i = 0; i < 4; ++i) onesu.u[i] = 0x3F803F80u;
  const s8v onesA = onesu.v;

  const int sr = tid >> 3;
  const int swz8 = (((tid & 7) ^ (sr & 7)) << 3);
  const int wbase = w * 512;

  f16v oacc[4] = {};
  f16v lacc = {};
  float mrun = -3e38f;

  auto stage = [&](int kb, int bufi) {
    const bf16* ksrc = Kf + kbase + (size_t)(kb * 64 + sr) * 128 + swz8;
    gload16(ksrc,      &Kls[bufi][wbase]);
    gload16(ksrc + 64, &Kls[bufi][4096 + wbase]);
    const bf16* vsrc = Vt + vbase + (size_t)sr * 2048 + kb * 64 + swz8;
    gload16(vsrc,                      &Vls[bufi][wbase]);
    gload16(vsrc + (size_t)64 * 2048,  &Vls[bufi][4096 + wbase]);
  };

  stage(0, 0);
  asm volatile("s_waitcnt vmcnt(0)" ::: "memory");
  __syncthreads();

  for (int kb = 0; kb < 32; ++kb) {
    const int bufi = kb & 1;
    if (kb + 1 < 32) stage(kb + 1, bufi ^ 1);

    const bf16* KB = Kls[bufi];
    const bf16* VB = Vls[bufi];

    // S^T = K[perm] . Q^T : sac[s][r] = P[perm(crow(r,h)) + 32s][q31]
    f16v sac[2] = {};
    __builtin_amdgcn_s_setprio(1);
#pragma unroll
    for (int c = 0; c < 8; ++c) {
      const int cc = 2 * c + h;
      const int cof = (cc >> 3) * 4096 + (((cc & 7) ^ rxK) << 3);
      s8v k0 = *(const s8v*)&KB[cof + pq * 64];
      s8v k1 = *(const s8v*)&KB[cof + (32 + pq) * 64];
      sac[0] = __builtin_amdgcn_mfma_f32_32x32x16_bf16(k0, qf[c], sac[0], 0, 0, 0);
      sac[1] = __builtin_amdgcn_mfma_f32_32x32x16_bf16(k1, qf[c], sac[1], 0, 0, 0);
    }
    __builtin_amdgcn_s_setprio(0);

    float pm = -3e38f;
#pragma unroll
    for (int r = 0; r < 16; ++r) {
      pm = fmaxf(pm, sac[0][r]);
      pm = fmaxf(pm, sac[1][r]);
    }
    pm = fmaxf(pm, __shfl_xor(pm, 32));

    const bool skip = __all(pm <= mrun + 8.0f);   // defer-max (T13)
    if (!skip) {
      const float mnew = fmaxf(mrun, pm);
      const float corr = exp2f(mrun - mnew);
      mrun = mnew;
#pragma unroll
      for (int r = 0; r < 16; ++r) lacc[r] *= corr;
#pragma unroll
      for (int m = 0; m < 4; ++m)
#pragma unroll
        for (int r = 0; r < 16; ++r) oacc[m][r] *= corr;
    }
#pragma unroll
    for (int s = 0; s < 2; ++s)
#pragma unroll
      for (int r = 0; r < 16; ++r)
        sac[s][r] = exp2f(sac[s][r] - mrun);

    // P -> bf16 B-frags: with the key permutation, F[ksg] is just the pack
    // of 8 consecutive sac values. No cross-lane ops.
    s8v F[4];
#pragma unroll
    for (int ksg = 0; ksg < 4; ++ksg) {
      const int s = ksg >> 1;
      const int u8 = (ksg & 1) << 3;
      union { u32 u[4]; s8v v; } fu;
#pragma unroll
      for (int t = 0; t < 4; ++t)
        fu.u[t] = pkbf(sac[s][u8 + 2 * t], sac[s][u8 + 2 * t + 1]);
      F[ksg] = fu.v;
    }

    __builtin_amdgcn_s_setprio(1);
#pragma unroll
    for (int ksg = 0; ksg < 4; ++ksg) {
      const int cc2 = 2 * ksg + h;
      const int vof = ((cc2 ^ rxV) << 3);
#pragma unroll
      for (int m = 0; m < 4; ++m) {
        s8v vf = *(const s8v*)&VB[(m * 32 + q31) * 64 + vof];
        oacc[m] = __builtin_amdgcn_mfma_f32_32x32x16_bf16(vf, F[ksg], oacc[m], 0, 0, 0);
      }
      lacc = __builtin_amdgcn_mfma_f32_32x32x16_bf16(onesA, F[ksg], lacc, 0, 0, 0);
    }
    __builtin_amdgcn_s_setprio(0);

    asm volatile("s_waitcnt vmcnt(0)" ::: "memory");
    __syncthreads();
  }

  const float inv = 1.f / lacc[0];
  bf16* orow = O + ((size_t)b * 1024 + qrow) * 4096 + hd * 128;
#pragma unroll
  for (int m = 0; m < 4; ++m)
#pragma unroll
    for (int r = 0; r < 16; r += 2) {
      const int d = m * 32 + (r & 3) + 8 * (r >> 2) + 4 * h;
      *(u32*)&orow[d] = pkbf(oacc[m][r] * inv, oacc[m][r + 1] * inv);
    }
}

// ------------------------------------------------------------------
extern "C" void kernel_launch(void* const* d_in, const int* in_sizes, int n_in,
                              void* d_out, int out_size, void* d_ws, size_t ws_size,
                              hipStream_t stream) {
  const float* x  = (const float*)d_in[0];
  const float* fc = (const float*)d_in[1];
  const float* fs = (const float*)d_in[2];
  const float* ck = (const float*)d_in[3];
  const float* cv = (const float*)d_in[4];
  const float* wq = (const float*)d_in[5];
  const float* wk = (const float*)d_in[6];
  const float* wv = (const float*)d_in[7];
  const float* wo = (const float*)d_in[8];
  float* out = (float*)d_out;

  char* ws = (char*)d_ws;
  bf16* qr    = (bf16*)(ws);                     // [4][32][1024][128]  32 MiB
  bf16* kfull = (bf16*)(ws + (32u << 20));       // [4][8][2048][128]   16 MiB
  bf16* vt    = (bf16*)(ws + (48u << 20));       // [4][8][128][2048]   16 MiB
  bf16* xb    = (bf16*)(ws + (64u << 20));       // [4096][4096]        32 MiB
  bf16* attn  = xb;                              // aliases xb (dead by then)
  bf16* wqb   = (bf16*)(ws + (96u << 20));       // [4096][4096]        32 MiB
  bf16* wob   = wqb;                             // aliases wqb (dead by then)
  bf16* wkvb  = (bf16*)(ws + (128u << 20));      // [2048][4096]        16 MiB

  hipFuncSetAttribute(reinterpret_cast<const void*>(&gemm256<MODE_Q>),
                      hipFuncAttributeMaxDynamicSharedMemorySize, 131072);
  hipFuncSetAttribute(reinterpret_cast<const void*>(&gemm256<MODE_OUT>),
                      hipFuncAttributeMaxDynamicSharedMemorySize, 131072);
  hipFuncSetAttribute(reinterpret_cast<const void*>(&gemm128kv),
                      hipFuncAttributeMaxDynamicSharedMemorySize, 98304);

  cvt_bf16<<<8192, 256, 0, stream>>>(x, xb);
  cvt_bf16<<<8192, 256, 0, stream>>>(wq, wqb);
  cvt_bf16<<<2048, 256, 0, stream>>>(wk, wkvb);
  cvt_bf16<<<2048, 256, 0, stream>>>(wv, wkvb + 4194304);
  cvt_cache_k<<<4096, 256, 0, stream>>>(ck, kfull);
  cvt_cache_v<<<4096, 256, 0, stream>>>(cv, vt);

  // Q scale = 1/sqrt(128) * log2(e)  (softmax computed in exp2 domain)
  gemm256<MODE_Q><<<dim3(16, 16), 512, 131072, stream>>>(
      xb, wqb, qr, 4096, 0.1275174198520337f);
  gemm128kv<<<dim3(32, 8), 512, 98304, stream>>>(xb, wkvb, kfull, vt, 4096);

  cvt_bf16<<<8192, 256, 0, stream>>>(wo, wob);   // after Q gemm: reuses wqb

  rope_kernel<<<32768, 256, 0, stream>>>(qr, fc, fs, 1024, 0);
  rope_kernel<<<8192, 256, 0, stream>>>(kfull, fc, fs, 2048, 1024);

  attn_kernel<<<dim3(4, 128), 512, 0, stream>>>(qr, kfull, vt, attn);

  gemm256<MODE_OUT><<<dim3(16, 16), 512, 131072, stream>>>(
      attn, wob, out, 4096, 1.0f);
}

// Round 10
// 615.841 us; speedup vs baseline: 1.0963x; 1.0044x over previous
//
#include <hip/hip_runtime.h>
#include <hip/hip_bf16.h>

using bf16 = __hip_bfloat16;
typedef __attribute__((ext_vector_type(4))) float f4;
typedef __attribute__((ext_vector_type(16))) float f16v;
typedef __attribute__((ext_vector_type(8))) short s8v;
typedef __attribute__((ext_vector_type(4))) short s4v;
typedef __attribute__((ext_vector_type(4))) unsigned int u4v;
typedef unsigned int u32;

__device__ __forceinline__ short f2bf(float x) {
  bf16 h = __float2bfloat16(x);
  return *reinterpret_cast<short*>(&h);
}

__device__ __forceinline__ u32 pkbf(float lo, float hi) {
  return (u32)(unsigned short)f2bf(lo) | ((u32)(unsigned short)f2bf(hi) << 16);
}

__device__ __forceinline__ void gload16(const bf16* g, bf16* l) {
  __builtin_amdgcn_global_load_lds(
      (const __attribute__((address_space(1))) u32*)g,
      (__attribute__((address_space(3))) u32*)l, 16, 0, 0);
}

// ------------------------------------------------------------------
// generic fp32 -> bf16, 8 elems/thread
__global__ __launch_bounds__(256) void cvt_bf16(const float* __restrict__ src,
                                                bf16* __restrict__ dst) {
  size_t e = ((size_t)blockIdx.x * 256 + threadIdx.x) << 3;
  f4 a = *(const f4*)(src + e);
  f4 b = *(const f4*)(src + e + 4);
  s8v r = { f2bf(a[0]), f2bf(a[1]), f2bf(a[2]), f2bf(a[3]),
            f2bf(b[0]), f2bf(b[1]), f2bf(b[2]), f2bf(b[3]) };
  *(s8v*)(dst + e) = r;
}

// cache_k [b][kv][p][d] f32 -> kfull [b][kv][p][d] bf16 (p < 1024)
__global__ __launch_bounds__(256) void cvt_cache_k(const float* __restrict__ src,
                                                   bf16* __restrict__ dst) {
  size_t e = ((size_t)blockIdx.x * 256 + threadIdx.x) << 2;
  f4 v = *(const f4*)(src + e);
  unsigned d = (unsigned)(e & 127u), p = (unsigned)((e >> 7) & 1023u), bk = (unsigned)(e >> 17);
  s4v r = { f2bf(v[0]), f2bf(v[1]), f2bf(v[2]), f2bf(v[3]) };
  *(s4v*)(dst + (((size_t)bk * 2048 + p) << 7) + d) = r;
}

// cache_v [b][kv][p][d] f32 -> vt [b][kv][d][p] bf16 (transposed, p < 1024)
__global__ __launch_bounds__(256) void cvt_cache_v(const float* __restrict__ src,
                                                   bf16* __restrict__ dst) {
  size_t e = ((size_t)blockIdx.x * 256 + threadIdx.x) << 2;
  unsigned p = (unsigned)(e & 1023u), d = (unsigned)((e >> 10) & 127u), bk = (unsigned)(e >> 17);
  const float* s = src + (((size_t)bk * 1024 + p) << 7) + d;
  s4v r = { f2bf(s[0]), f2bf(s[128]), f2bf(s[256]), f2bf(s[384]) };
  *(s4v*)(dst + (((size_t)bk * 128 + d) << 11) + p) = r;
}

// ------------------------------------------------------------------
// in-place RoPE on bf16 buffer laid out [hh][sstride][128]; rows soff+s
__global__ __launch_bounds__(256) void rope_kernel(bf16* __restrict__ buf,
                                                   const float* __restrict__ fc,
                                                   const float* __restrict__ fs,
                                                   int sstride, int soff) {
  size_t t = (size_t)blockIdx.x * 256 + threadIdx.x;
  unsigned ip = (unsigned)(t & 63u);
  unsigned s  = (unsigned)((t >> 6) & 1023u);
  unsigned hh = (unsigned)(t >> 16);
  size_t base = ((size_t)hh * sstride + soff + s) * 128 + 2 * ip;
  unsigned u = *(unsigned*)(buf + base);
  float xr = __uint_as_float(u << 16);
  float xi = __uint_as_float(u & 0xffff0000u);
  float c = fc[s * 64 + ip], sn = fs[s * 64 + ip];
  unsigned short r0 = (unsigned short)f2bf(xr * c - xi * sn);
  unsigned short r1 = (unsigned short)f2bf(xr * sn + xi * c);
  *(unsigned*)(buf + base) = (unsigned)r0 | ((unsigned)r1 << 16);
}

// ------------------------------------------------------------------
// 256x256-tile GEMM, BK=64, 8-phase schedule (R4-proven distributed prefetch).
#define MODE_Q   0
#define MODE_OUT 1

#define PHASE_TAIL(AC, BC, KS, MH)                                           \
  {                                                                          \
    s8v af[4], bv[4];                                                        \
    const int cofs = ((((KS) * 4) | g) ^ fx) << 3;                           \
    _Pragma("unroll") for (int mi = 0; mi < 4; ++mi)                         \
        af[mi] = *(const s8v*)&(AC)[aRowBase + ((MH)*4 + mi) * 1024 + cofs]; \
    _Pragma("unroll") for (int ni = 0; ni < 4; ++ni)                         \
        bv[ni] = *(const s8v*)&(BC)[bRowBase + ni * 1024 + cofs];            \
    __builtin_amdgcn_s_barrier();                                            \
    asm volatile("s_waitcnt lgkmcnt(0)" ::: "memory");                       \
    __builtin_amdgcn_s_setprio(1);                                           \
    _Pragma("unroll") for (int mi = 0; mi < 4; ++mi)                         \
      _Pragma("unroll") for (int ni = 0; ni < 4; ++ni)                       \
          acc[(MH)*4 + mi][ni] = __builtin_amdgcn_mfma_f32_16x16x32_bf16(    \
              af[mi], bv[ni], acc[(MH)*4 + mi][ni], 0, 0, 0);                \
    __builtin_amdgcn_s_setprio(0);                                           \
    __builtin_amdgcn_s_barrier();                                            \
  }

#define PHASE_HEAD(AC, BC)                                                   \
  {                                                                          \
    __builtin_amdgcn_s_barrier();                                            \
    s8v af[4], bv[4];                                                        \
    const int cofs = (g ^ fx) << 3;                                          \
    _Pragma("unroll") for (int mi = 0; mi < 4; ++mi)                         \
        af[mi] = *(const s8v*)&(AC)[aRowBase + mi * 1024 + cofs];            \
    _Pragma("unroll") for (int ni = 0; ni < 4; ++ni)                         \
        bv[ni] = *(const s8v*)&(BC)[bRowBase + ni * 1024 + cofs];            \
    asm volatile("s_waitcnt lgkmcnt(0)" ::: "memory");                       \
    __builtin_amdgcn_s_setprio(1);                                           \
    _Pragma("unroll") for (int mi = 0; mi < 4; ++mi)                         \
      _Pragma("unroll") for (int ni = 0; ni < 4; ++ni)                       \
          acc[mi][ni] = __builtin_amdgcn_mfma_f32_16x16x32_bf16(             \
              af[mi], bv[ni], acc[mi][ni], 0, 0, 0);                         \
    __builtin_amdgcn_s_setprio(0);                                           \
    __builtin_amdgcn_s_barrier();                                            \
  }

#define KTILE(AC, BC, PA, PB, NA, NB, PF)                                    \
  {                                                                          \
    if (PF) { gload16((NA), (PA)); gload16((NA) + rstep, (PA) + 4096); }     \
    if (PF) asm volatile("s_waitcnt vmcnt(2)" ::: "memory");                 \
    else    asm volatile("s_waitcnt vmcnt(0)" ::: "memory");                 \
    PHASE_HEAD(AC, BC)                                                       \
    if (PF) { gload16((NA) + 2 * rstep, (PA) + 8192);                        \
              gload16((NA) + 3 * rstep, (PA) + 12288); }                     \
    PHASE_TAIL(AC, BC, 0, 1)                                                 \
    if (PF) { gload16((NB), (PB)); gload16((NB) + rstep, (PB) + 4096); }     \
    PHASE_TAIL(AC, BC, 1, 0)                                                 \
    if (PF) { gload16((NB) + 2 * rstep, (PB) + 8192);                        \
              gload16((NB) + 3 * rstep, (PB) + 12288); }                     \
    PHASE_TAIL(AC, BC, 1, 1)                                                 \
  }

template <int MODE>
__global__ __launch_bounds__(512, 2) void gemm256(const bf16* __restrict__ A,
                                                  const bf16* __restrict__ B,
                                                  void* __restrict__ o1,
                                                  int K, float scale) {
  extern __shared__ bf16 smem[];
  bf16* A0 = smem;
  bf16* A1 = smem + 16384;
  bf16* B0 = smem + 32768;
  bf16* B1 = smem + 49152;

  const int tid = threadIdx.x;
  const int lane = tid & 63;
  const int wid = tid >> 6;
  const int wm = wid >> 2, wn = wid & 3;
  const int fr = lane & 15;
  const int g = lane >> 4;
  const int rg = g << 2;
  const int fx = lane & 7;

  // XCD-bijective block swizzle (nwg % 8 == 0)
  const int gy = gridDim.y;
  int lin = blockIdx.y * gridDim.x + blockIdx.x;
  const int qq = (gridDim.x * gy) >> 3;
  lin = (lin & 7) * qq + (lin >> 3);
  const int bm = lin / gy;
  const int bn = lin % gy;

  const int r0 = tid >> 3;
  const int sc = (tid & 7) ^ (r0 & 7);
  const bf16* aptr = A + (size_t)(bm * 256 + r0) * K + sc * 8;
  const bf16* bptr = B + (size_t)(bn * 256 + r0) * K + sc * 8;
  const size_t rstep = (size_t)64 * K;
  const int wofs = (tid & 448) << 3;
  bf16* pA0 = A0 + wofs; bf16* pA1 = A1 + wofs;
  bf16* pB0 = B0 + wofs; bf16* pB1 = B1 + wofs;

  const int aRowBase = (wm * 128 + fr) * 64;
  const int bRowBase = (wn * 64 + fr) * 64;

  f4 acc[8][4] = {};

#pragma unroll
  for (int i = 0; i < 4; ++i) gload16(aptr + i * rstep, pA0 + i * 4096);
#pragma unroll
  for (int i = 0; i < 4; ++i) gload16(bptr + i * rstep, pB0 + i * 4096);

  const int nk = K >> 6;
  for (int kt = 0; kt < nk; kt += 2) {
    const bf16* na = aptr + (kt + 1) * 64;
    const bf16* nb = bptr + (kt + 1) * 64;
    KTILE(A0, B0, pA1, pB1, na, nb, true)
    const bool pf2 = (kt + 2 < nk);
    const bf16* na2 = aptr + (kt + 2) * 64;
    const bf16* nb2 = bptr + (kt + 2) * 64;
    KTILE(A1, B1, pA0, pB0, na2, nb2, pf2)
  }

#pragma unroll
  for (int m = 0; m < 8; ++m) {
    const int grow0 = bm * 256 + wm * 128 + m * 16 + rg;
    const int b = grow0 >> 10, s0 = grow0 & 1023;
#pragma unroll
    for (int n = 0; n < 4; ++n) {
      const int gcol = bn * 256 + wn * 64 + n * 16 + fr;
      if constexpr (MODE == MODE_OUT) {
#pragma unroll
        for (int j = 0; j < 4; ++j)
          ((float*)o1)[(size_t)(grow0 + j) * 4096 + gcol] = acc[m][n][j];
      } else {  // MODE_Q (scaled scatter to [b][h][s][d])
        const int h = gcol >> 7, d = gcol & 127;
#pragma unroll
        for (int j = 0; j < 4; ++j)
          ((bf16*)o1)[((((size_t)b * 32 + h) << 10) + s0 + j) * 128 + d] =
              __float2bfloat16(acc[m][n][j] * scale);
      }
    }
  }
}

// ------------------------------------------------------------------
// 128x256-tile GEMM for the KV projection (N=2048): grid 32x8 = 256 blocks.
#define PH128(AC, BC, KS, OPEN)                                              \
  {                                                                          \
    if (OPEN) __builtin_amdgcn_s_barrier();                                  \
    s8v af[4], bv[4];                                                        \
    const int cofs = ((((KS) * 4) | g) ^ fx) << 3;                           \
    _Pragma("unroll") for (int mi = 0; mi < 4; ++mi)                         \
        af[mi] = *(const s8v*)&(AC)[aRowBase + mi * 1024 + cofs];            \
    _Pragma("unroll") for (int ni = 0; ni < 4; ++ni)                         \
        bv[ni] = *(const s8v*)&(BC)[bRowBase + ni * 1024 + cofs];            \
    if (!(OPEN)) __builtin_amdgcn_s_barrier();                               \
    asm volatile("s_waitcnt lgkmcnt(0)" ::: "memory");                       \
    __builtin_amdgcn_s_setprio(1);                                           \
    _Pragma("unroll") for (int mi = 0; mi < 4; ++mi)                         \
      _Pragma("unroll") for (int ni = 0; ni < 4; ++ni)                       \
          acc[mi][ni] = __builtin_amdgcn_mfma_f32_16x16x32_bf16(             \
              af[mi], bv[ni], acc[mi][ni], 0, 0, 0);                         \
    __builtin_amdgcn_s_setprio(0);                                           \
    __builtin_amdgcn_s_barrier();                                            \
  }

#define KTILE128(AC, BC, PA, PB, NA, NB, PF)                                 \
  {                                                                          \
    if (PF) { gload16((NB), (PB)); gload16((NB) + rstep, (PB) + 4096); }     \
    if (PF) asm volatile("s_waitcnt vmcnt(2)" ::: "memory");                 \
    else    asm volatile("s_waitcnt vmcnt(0)" ::: "memory");                 \
    PH128(AC, BC, 0, true)                                                   \
    if (PF) { gload16((NB) + 2 * rstep, (PB) + 8192);                        \
              gload16((NB) + 3 * rstep, (PB) + 12288);                       \
              gload16((NA), (PA)); gload16((NA) + rstep, (PA) + 4096); }     \
    PH128(AC, BC, 1, false)                                                  \
  }

__global__ __launch_bounds__(512, 2) void gemm128kv(const bf16* __restrict__ A,
                                                    const bf16* __restrict__ B,
                                                    bf16* __restrict__ kout,
                                                    bf16* __restrict__ vout,
                                                    int K) {
  extern __shared__ bf16 smem[];
  bf16* A0 = smem;
  bf16* A1 = smem + 8192;
  bf16* B0 = smem + 16384;
  bf16* B1 = smem + 32768;

  const int tid = threadIdx.x;
  const int lane = tid & 63;
  const int wid = tid >> 6;
  const int wm = wid >> 2, wn = wid & 3;
  const int fr = lane & 15;
  const int g = lane >> 4;
  const int rg = g << 2;
  const int fx = lane & 7;

  const int gy = gridDim.y;
  int lin = blockIdx.y * gridDim.x + blockIdx.x;
  const int qq = (gridDim.x * gy) >> 3;
  lin = (lin & 7) * qq + (lin >> 3);
  const int bm = lin / gy;
  const int bn = lin % gy;

  const int r0 = tid >> 3;
  const int sc = (tid & 7) ^ (r0 & 7);
  const bf16* aptr = A + (size_t)(bm * 128 + r0) * K + sc * 8;
  const bf16* bptr = B + (size_t)(bn * 256 + r0) * K + sc * 8;
  const size_t rstep = (size_t)64 * K;
  const int wofs = (tid & 448) << 3;
  bf16* pA0 = A0 + wofs; bf16* pA1 = A1 + wofs;
  bf16* pB0 = B0 + wofs; bf16* pB1 = B1 + wofs;

  const int aRowBase = (wm * 64 + fr) * 64;
  const int bRowBase = (wn * 64 + fr) * 64;

  f4 acc[4][4] = {};

  gload16(aptr, pA0); gload16(aptr + rstep, pA0 + 4096);
#pragma unroll
  for (int i = 0; i < 4; ++i) gload16(bptr + i * rstep, pB0 + i * 4096);

  const int nk = K >> 6;
  for (int kt = 0; kt < nk; kt += 2) {
    const bf16* na = aptr + (kt + 1) * 64;
    const bf16* nb = bptr + (kt + 1) * 64;
    KTILE128(A0, B0, pA1, pB1, na, nb, true)
    const bool pf2 = (kt + 2 < nk);
    const bf16* na2 = aptr + (kt + 2) * 64;
    const bf16* nb2 = bptr + (kt + 2) * 64;
    KTILE128(A1, B1, pA0, pB0, na2, nb2, pf2)
  }

  // epilogue: cols 0..1023 = K proj, 1024..2047 = V proj (transposed write)
#pragma unroll
  for (int m = 0; m < 4; ++m) {
    const int grow0 = bm * 128 + wm * 64 + m * 16 + rg;
    const int b = grow0 >> 10, s0 = grow0 & 1023;
#pragma unroll
    for (int n = 0; n < 4; ++n) {
      const int gcol = bn * 256 + wn * 64 + n * 16 + fr;
      if (gcol < 1024) {
        const int hv = gcol >> 7, d = gcol & 127;
#pragma unroll
        for (int j = 0; j < 4; ++j)
          kout[(((size_t)b * 8 + hv) * 2048 + 1024 + s0 + j) * 128 + d] =
              __float2bfloat16(acc[m][n][j]);
      } else {
        const int c = gcol - 1024, hv = c >> 7, d = c & 127;
        s4v r = { f2bf(acc[m][n][0]), f2bf(acc[m][n][1]),
                  f2bf(acc[m][n][2]), f2bf(acc[m][n][3]) };
        *(s4v*)(vout + (((size_t)b * 8 + hv) * 128 + d) * 2048 + 1024 + s0) = r;
      }
    }
  }
}

// ------------------------------------------------------------------
// Flash attention, 8 waves x 32 q-rows, 32x32x16 MFMA, swapped QK^T and PV,
// key-permuted (R9). NEW: conflict-free LDS geometry — 128-elem (256 B, 16
// slot) rows with mod-16 XOR swizzle.
//   K LDS: [64 key][128 d]; slot s of row r holds d-chunk s^(r&15).
//   V LDS: [64 row'][128]; row' = d>>1, col = (d&1)*64 + k; slot s of row r'
//          holds col-chunk s^(r'&15).
// Any 16-lane phase group reads 16 distinct slots -> zero bank conflicts.
__global__ __launch_bounds__(512) void attn_kernel(const bf16* __restrict__ Q,
                                                   const bf16* __restrict__ Kf,
                                                   const bf16* __restrict__ Vt,
                                                   bf16* __restrict__ O) {
  __shared__ alignas(16) bf16 Kls[2][8192];
  __shared__ alignas(16) bf16 Vls[2][8192];

  const int tid = threadIdx.x;
  const int lane = tid & 63;
  const int w = tid >> 6;
  const int h = lane >> 5;
  const int q31 = lane & 31;
  // permuted key row: swap bits 2 and 3 of q31
  const int pq = (q31 & 19) | ((q31 & 4) << 1) | ((q31 & 8) >> 1);
  const int rxK = pq & 15;          // K read swizzle key (rows distinct mod 16)
  const int rowv = q31 >> 1;        // V read row' within 16-row subtile
  const int dpar = (q31 & 1) << 3;  // d parity -> slot bit 3

  int lin = blockIdx.y * 4 + blockIdx.x;               // 0..511
  lin = (lin & 7) * 64 + (lin >> 3);
  const int qb = lin & 3;
  const int hrem = (lin >> 2) & 3;
  const int pair = lin >> 4;                            // 0..31
  const int b = pair >> 3, kv = pair & 7;
  const int hd = kv * 4 + hrem;

  const size_t qbase = (((size_t)b * 32 + hd) << 10) * 128;
  const size_t kbase = (((size_t)b * 8 + kv) * 2048) * 128;
  const size_t vbase = (((size_t)b * 8 + kv) * 128) * 2048;

  const int qrow = qb * 256 + w * 32 + q31;
  s8v qf[8];
#pragma unroll
  for (int c = 0; c < 8; ++c)
    qf[c] = *(const s8v*)&Q[qbase + (size_t)qrow * 128 + c * 16 + h * 8];

  // ones A-fragment for the row-sum MFMA
  union { u32 u[4]; s8v v; } onesu;
#pragma unroll
  for (int i = 0; i < 4; ++i) onesu.u[i] = 0x3F803F80u;
  const s8v onesA = onesu.v;

  // staging: thread covers row (tid>>4) slot (tid&15); content chunk =
  // (tid&15) ^ ((tid>>4)&15). Pass 1 adds 32 rows (K: +32 keys, V: +64 d).
  const int sk = (tid >> 4) & 15;
  const int kch = (tid & 15) ^ sk;
  const int wbase = w * 512;
  const size_t vrow0 = (size_t)(2 * (tid >> 4) + (kch >> 3)) * 2048 + (kch & 7) * 8;

  f16v oacc[4] = {};
  f16v lacc = {};
  float mrun = -3e38f;

  auto stage = [&](int kb, int bufi) {
    const bf16* ksrc = Kf + kbase + (size_t)(kb * 64 + (tid >> 4)) * 128 + kch * 8;
    gload16(ksrc,            &Kls[bufi][wbase]);
    gload16(ksrc + 32 * 128, &Kls[bufi][4096 + wbase]);
    const bf16* vsrc = Vt + vbase + vrow0 + kb * 64;
    gload16(vsrc,             &Vls[bufi][wbase]);
    gload16(vsrc + 64 * 2048, &Vls[bufi][4096 + wbase]);
  };

  stage(0, 0);
  asm volatile("s_waitcnt vmcnt(0)" ::: "memory");
  __syncthreads();

  for (int kb = 0; kb < 32; ++kb) {
    const int bufi = kb & 1;
    if (kb + 1 < 32) stage(kb + 1, bufi ^ 1);

    const bf16* KB = Kls[bufi];
    const bf16* VB = Vls[bufi];

    // S^T = K[perm] . Q^T
    f16v sac[2] = {};
    __builtin_amdgcn_s_setprio(1);
#pragma unroll
    for (int c = 0; c < 8; ++c) {
      const int cc = 2 * c + h;
      const int cof = ((cc ^ rxK) << 3);
      s8v k0 = *(const s8v*)&KB[pq * 128 + cof];
      s8v k1 = *(const s8v*)&KB[(32 + pq) * 128 + cof];
      sac[0] = __builtin_amdgcn_mfma_f32_32x32x16_bf16(k0, qf[c], sac[0], 0, 0, 0);
      sac[1] = __builtin_amdgcn_mfma_f32_32x32x16_bf16(k1, qf[c], sac[1], 0, 0, 0);
    }
    __builtin_amdgcn_s_setprio(0);

    float pm = -3e38f;
#pragma unroll
    for (int r = 0; r < 16; ++r) {
      pm = fmaxf(pm, sac[0][r]);
      pm = fmaxf(pm, sac[1][r]);
    }
    pm = fmaxf(pm, __shfl_xor(pm, 32));

    const bool skip = __all(pm <= mrun + 8.0f);   // defer-max (T13)
    if (!skip) {
      const float mnew = fmaxf(mrun, pm);
      const float corr = exp2f(mrun - mnew);
      mrun = mnew;
#pragma unroll
      for (int r = 0; r < 16; ++r) lacc[r] *= corr;
#pragma unroll
      for (int m = 0; m < 4; ++m)
#pragma unroll
        for (int r = 0; r < 16; ++r) oacc[m][r] *= corr;
    }
#pragma unroll
    for (int s = 0; s < 2; ++s)
#pragma unroll
      for (int r = 0; r < 16; ++r)
        sac[s][r] = exp2f(sac[s][r] - mrun);

    // P -> bf16 B-frags: key permutation makes F[ksg] = 8 consecutive sacs.
    s8v F[4];
#pragma unroll
    for (int ksg = 0; ksg < 4; ++ksg) {
      const int s = ksg >> 1;
      const int u8 = (ksg & 1) << 3;
      union { u32 u[4]; s8v v; } fu;
#pragma unroll
      for (int t = 0; t < 4; ++t)
        fu.u[t] = pkbf(sac[s][u8 + 2 * t], sac[s][u8 + 2 * t + 1]);
      F[ksg] = fu.v;
    }

    __builtin_amdgcn_s_setprio(1);
#pragma unroll
    for (int ksg = 0; ksg < 4; ++ksg) {
      const int cc2 = 2 * ksg + h;
      const int vof = (((dpar | cc2) ^ rowv) << 3);
#pragma unroll
      for (int m = 0; m < 4; ++m) {
        s8v vf = *(const s8v*)&VB[(m * 16 + rowv) * 128 + vof];
        oacc[m] = __builtin_amdgcn_mfma_f32_32x32x16_bf16(vf, F[ksg], oacc[m], 0, 0, 0);
      }
      lacc = __builtin_amdgcn_mfma_f32_32x32x16_bf16(onesA, F[ksg], lacc, 0, 0, 0);
    }
    __builtin_amdgcn_s_setprio(0);

    asm volatile("s_waitcnt vmcnt(0)" ::: "memory");
    __syncthreads();
  }

  const float inv = 1.f / lacc[0];
  bf16* orow = O + ((size_t)b * 1024 + qrow) * 4096 + hd * 128;
#pragma unroll
  for (int m = 0; m < 4; ++m)
#pragma unroll
    for (int r = 0; r < 16; r += 2) {
      const int d = m * 32 + (r & 3) + 8 * (r >> 2) + 4 * h;
      *(u32*)&orow[d] = pkbf(oacc[m][r] * inv, oacc[m][r + 1] * inv);
    }
}

// ------------------------------------------------------------------
extern "C" void kernel_launch(void* const* d_in, const int* in_sizes, int n_in,
                              void* d_out, int out_size, void* d_ws, size_t ws_size,
                              hipStream_t stream) {
  const float* x  = (const float*)d_in[0];
  const float* fc = (const float*)d_in[1];
  const float* fs = (const float*)d_in[2];
  const float* ck = (const float*)d_in[3];
  const float* cv = (const float*)d_in[4];
  const float* wq = (const float*)d_in[5];
  const float* wk = (const float*)d_in[6];
  const float* wv = (const float*)d_in[7];
  const float* wo = (const float*)d_in[8];
  float* out = (float*)d_out;

  char* ws = (char*)d_ws;
  bf16* qr    = (bf16*)(ws);                     // [4][32][1024][128]  32 MiB
  bf16* kfull = (bf16*)(ws + (32u << 20));       // [4][8][2048][128]   16 MiB
  bf16* vt    = (bf16*)(ws + (48u << 20));       // [4][8][128][2048]   16 MiB
  bf16* xb    = (bf16*)(ws + (64u << 20));       // [4096][4096]        32 MiB
  bf16* attn  = xb;                              // aliases xb (dead by then)
  bf16* wqb   = (bf16*)(ws + (96u << 20));       // [4096][4096]        32 MiB
  bf16* wob   = wqb;                             // aliases wqb (dead by then)
  bf16* wkvb  = (bf16*)(ws + (128u << 20));      // [2048][4096]        16 MiB

  hipFuncSetAttribute(reinterpret_cast<const void*>(&gemm256<MODE_Q>),
                      hipFuncAttributeMaxDynamicSharedMemorySize, 131072);
  hipFuncSetAttribute(reinterpret_cast<const void*>(&gemm256<MODE_OUT>),
                      hipFuncAttributeMaxDynamicSharedMemorySize, 131072);
  hipFuncSetAttribute(reinterpret_cast<const void*>(&gemm128kv),
                      hipFuncAttributeMaxDynamicSharedMemorySize, 98304);

  cvt_bf16<<<8192, 256, 0, stream>>>(x, xb);
  cvt_bf16<<<8192, 256, 0, stream>>>(wq, wqb);
  cvt_bf16<<<2048, 256, 0, stream>>>(wk, wkvb);
  cvt_bf16<<<2048, 256, 0, stream>>>(wv, wkvb + 4194304);
  cvt_cache_k<<<4096, 256, 0, stream>>>(ck, kfull);
  cvt_cache_v<<<4096, 256, 0, stream>>>(cv, vt);

  // Q scale = 1/sqrt(128) * log2(e)  (softmax computed in exp2 domain)
  gemm256<MODE_Q><<<dim3(16, 16), 512, 131072, stream>>>(
      xb, wqb, qr, 4096, 0.1275174198520337f);
  gemm128kv<<<dim3(32, 8), 512, 98304, stream>>>(xb, wkvb, kfull, vt, 4096);

  cvt_bf16<<<8192, 256, 0, stream>>>(wo, wob);   // after Q gemm: reuses wqb

  rope_kernel<<<32768, 256, 0, stream>>>(qr, fc, fs, 1024, 0);
  rope_kernel<<<8192, 256, 0, stream>>>(kfull, fc, fs, 2048, 1024);

  attn_kernel<<<dim3(4, 128), 512, 0, stream>>>(qr, kfull, vt, attn);

  gemm256<MODE_OUT><<<dim3(16, 16), 512, 131072, stream>>>(
      attn, wob, out, 4096, 1.0f);
}